// Round 17
// baseline (4425.550 us; speedup 1.0000x reference)
//
#include <hip/hip_runtime.h>
#include <math.h>

#define N_     64
#define Mn     2
#define Tn     300
#define Vn     25
#define Kk     3
#define CIN    3
#define CE     64
#define INTER_ 16
#define TV     7500
#define VV     625
#define ESEG   5      /* enc att t-segments (60 t each) */
#define DSEG   15     /* dec att t-segments (20 t each) */
#define EYB    12     /* ey_stat t-blocks (25 t each) */

typedef float f4 __attribute__((ext_vector_type(4)));
typedef float f2 __attribute__((ext_vector_type(2)));

/* ---------------- workspace layout (float offsets) ----------------
 * region0: att partials 2*N*K*ESEG*VV = 1,200,000 (exactly) ;
 *          decy0 partials 2*N*60*128 = 983,040.
 * datt partials (2*N*K*DSEG*VV = 3.6M) live in d_out (dead until decy1). */
#define OFF_ATTP  0L
#define OFF_PART  0L
#define OFF_ATTEP 1200000L   /* [2] 268,800 */
#define OFF_ATTDP 1468800L   /* [2] 307,200 */
#define OFF_COV   1776000L   /* doubles: 2*120*9 -> 4320 floats */
#define OFF_PCT   1780320L   /* [2][6][64] = 768 */
#define OFF_YC    1781088L   /* 256 */
#define OFF_TST   1781344L   /* 600 */
#define OFF_DWDT  1781944L   /* 12288 */
#define OFF_WABT  1794232L   /* 6144 */
#define WS_REQ    1800376L

#define AEP_BR 134400   /* attEp branch stride (floats) */
#define ADP_BR 153600   /* attDp branch stride */

/* =================================================================
 * ENC ATT partials — batched over branches
 * ================================================================= */
__global__ __launch_bounds__(640)
void att_kernel(const float* __restrict__ x,
                const float* __restrict__ wa, const float* __restrict__ ba,
                const float* __restrict__ wb, const float* __restrict__ bb,
                float* __restrict__ att_partial)
{
    int b = blockIdx.x;
    int s = b % ESEG;
    int k = (b / ESEG) % Kk;
    int n = (b / (ESEG * Kk)) % N_;
    int br = b / (ESEG * Kk * N_);
    const float* xp = x + (long)br * (CIN * TV) + (long)n * (Mn * CIN * TV);

    __shared__ float xs[CIN][Vn];
    __shared__ float fa_s[INTER_][Vn];
    __shared__ float fb_s[INTER_][Vn];

    int tid = threadIdx.x;
    float acc = 0.f;
    const int TSEG = Tn / ESEG;
    int t0 = s * TSEG;
    for (int t = t0; t < t0 + TSEG; ++t) {
        __syncthreads();
        for (int idx = tid; idx < CIN * Vn; idx += 640) {
            int c = idx / Vn, v = idx % Vn;
            xs[c][v] = xp[(long)c * TV + t * Vn + v];
        }
        __syncthreads();
        for (int idx = tid; idx < 2 * INTER_ * Vn; idx += 640) {
            int j = idx;
            const float* w; const float* bias; float (*dst)[Vn];
            if (j < INTER_ * Vn) { w = wa; bias = ba; dst = fa_s; }
            else { j -= INTER_ * Vn; w = wb; bias = bb; dst = fb_s; }
            int i = j / Vn, v = j % Vn;
            float sum = bias[k * INTER_ + i];
            const float* wr = w + (k * INTER_ + i) * CIN;
            #pragma unroll
            for (int c = 0; c < CIN; ++c) sum += wr[c] * xs[c][v];
            dst[i][v] = sum;
        }
        __syncthreads();
        if (tid < VV) {
            int v = tid / Vn, w = tid % Vn;
            float a = 0.f;
            #pragma unroll
            for (int i = 0; i < INTER_; ++i) a += fa_s[i][v] * fb_s[i][w];
            acc += a;
        }
    }
    if (tid < VV)
        att_partial[(((long)((br * N_ + n) * Kk + k)) * ESEG + s) * VV + tid] = acc;
}

/* softmax over v per (br,n,k,w), then + (A+PA); writes PADDED layout. */
template<int SEGS, int PADW>
__global__ __launch_bounds__(256)
void softmax_kernel(const float* __restrict__ att_partial,
                    const float* __restrict__ A, const float* __restrict__ PA,
                    float* __restrict__ attP)
{
    int b = blockIdx.x;
    int k = b % Kk;
    __shared__ float as[VV];
    int tid = threadIdx.x;
    for (int idx = tid; idx < VV; idx += 256) {
        float s = 0.f;
        for (int seg = 0; seg < SEGS; ++seg)
            s += att_partial[((long)b * SEGS + seg) * VV + idx];
        as[idx] = s * (1.0f / (INTER_ * Tn));
    }
    __syncthreads();
    if (tid < Vn) {
        int w = tid;
        float m = -1e30f;
        #pragma unroll
        for (int v = 0; v < Vn; ++v) m = fmaxf(m, as[v * Vn + w]);
        float e[Vn];
        float den = 0.f;
        #pragma unroll
        for (int v = 0; v < Vn; ++v) { e[v] = expf(as[v * Vn + w] - m); den += e[v]; }
        float inv = 1.f / den;
        #pragma unroll
        for (int v = 0; v < Vn; ++v)
            attP[((long)b * Vn + v) * PADW + w] =
                e[v] * inv + A[k * VV + v * Vn + w] + PA[k * VV + v * Vn + w];
    } else if (tid < PADW) {
        #pragma unroll
        for (int v = 0; v < Vn; ++v)
            attP[((long)b * Vn + v) * PADW + tid] = 0.f;
    }
}

/* x covariance partials — batched: grid 240, 120 per branch */
__global__ __launch_bounds__(256)
void xcov_kernel(const float* __restrict__ x, double* __restrict__ part)
{
    int br = blockIdx.x / 120, g = blockIdx.x % 120;
    const float* xbase = x + (long)br * (CIN * TV);
    double a[9];
    #pragma unroll
    for (int q = 0; q < 9; ++q) a[q] = 0.0;
    for (long idx = (long)g * 256 + threadIdx.x; idx < (long)N_ * TV;
         idx += 120L * 256) {
        int n = (int)(idx / TV);
        int j = (int)(idx % TV);
        const float* xp = xbase + (long)n * (Mn * CIN * TV) + j;
        float x0 = xp[0], x1 = xp[TV], x2 = xp[2 * TV];
        a[0] += x0; a[1] += x1; a[2] += x2;
        a[3] += (double)x0 * x0; a[4] += (double)x0 * x1; a[5] += (double)x0 * x2;
        a[6] += (double)x1 * x1; a[7] += (double)x1 * x2; a[8] += (double)x2 * x2;
    }
    __shared__ double red[256];
    int tid = threadIdx.x;
    for (int q = 0; q < 9; ++q) {
        red[tid] = a[q];
        __syncthreads();
        for (int off = 128; off > 0; off >>= 1) {
            if (tid < off) red[tid] += red[tid + off];
            __syncthreads();
        }
        if (tid == 0) part[(long)blockIdx.x * 9 + q] = red[0];
        __syncthreads();
    }
}

/* ENC y stats — batched: grid 2*N*EYB */
__global__ __launch_bounds__(256)
void ey_stat_kernel(const float* __restrict__ x, const float* __restrict__ attEpB,
                    const float* __restrict__ ewd, float* __restrict__ part)
{
    __shared__ float attE_s[Kk][Vn][Vn];
    __shared__ float ewd_s[Kk * CE * CIN];
    __shared__ float xs[CIN][Vn];
    __shared__ float ez[Kk * CIN * Vn];
    __shared__ float ys[CE][Vn];
    int b = blockIdx.x, tb = b % EYB, n = (b / EYB) % N_, br = b / (EYB * N_);
    const float* attEp = attEpB + (long)br * AEP_BR;
    const float* xb = x + (long)br * (CIN * TV);
    int tid = threadIdx.x;
    for (int i = tid; i < Kk * VV; i += 256) {
        int k = i / 625, r = i - k * 625, v = r / 25, w = r - (r / 25) * 25;
        ((float*)attE_s)[i] = attEp[(long)n * 2100 + (k * 25 + v) * 28 + w];
    }
    for (int i = tid; i < Kk * CE * CIN; i += 256) ewd_s[i] = ewd[i];
    float s1 = 0.f, s2 = 0.f;
    for (int t = tb * 25; t < tb * 25 + 25; ++t) {
        const float* xp = xb + (long)n * (Mn * CIN * TV) + t * Vn;
        __syncthreads();
        for (int i = tid; i < CIN * Vn; i += 256) { int c = i / Vn, v = i % Vn; xs[c][v] = xp[c * TV + v]; }
        __syncthreads();
        for (int i = tid; i < Kk * CIN * Vn; i += 256) {
            int w = i % Vn, c = (i / Vn) % CIN, k = i / (Vn * CIN);
            float s = 0.f;
            #pragma unroll
            for (int v = 0; v < Vn; ++v) s += xs[c][v] * attE_s[k][v][w];
            ez[i] = s;
        }
        __syncthreads();
        for (int i = tid; i < CE * Vn; i += 256) {
            int w = i % Vn, o = i / Vn;
            float y = 0.f;
            #pragma unroll
            for (int k = 0; k < Kk; ++k)
                #pragma unroll
                for (int c = 0; c < CIN; ++c)
                    y += ewd_s[(k * CE + o) * CIN + c] * ez[(k * CIN + c) * Vn + w];
            ys[o][w] = y;
        }
        __syncthreads();
        if (tid < CE) {
            #pragma unroll
            for (int w = 0; w < Vn; ++w) { float y = ys[tid][w]; s1 += y; s2 += y * y; }
        }
    }
    if (tid < CE) { part[(long)b * 128 + tid * 2] = s1; part[(long)b * 128 + tid * 2 + 1] = s2; }
}

/* ENC finalize — batched: 2 blocks (one per branch) */
__global__ __launch_bounds__(64)
void enc_fin_kernel(const float* __restrict__ partB,
                    const double* __restrict__ covpB,
                    const float* __restrict__ eg, const float* __restrict__ ebt,
                    const float* __restrict__ edw, const float* __restrict__ edb,
                    const float* __restrict__ edg, const float* __restrict__ edbt,
                    float* __restrict__ pcTB)
{
    int br = blockIdx.x;
    const float* part = partB + (long)br * (N_ * EYB * 128);
    const double* covp = covpB + (long)br * (120 * 9);
    float* pcT = pcTB + br * 384;
    int o = threadIdx.x;
    __shared__ double tot[9];
    if (o < 9) { double s = 0; for (int g = 0; g < 120; ++g) s += covp[(long)g * 9 + o]; tot[o] = s; }
    double s1 = 0, s2 = 0;
    for (int b = 0; b < N_ * EYB; ++b) { s1 += part[(long)b * 128 + o * 2]; s2 += part[(long)b * 128 + o * 2 + 1]; }
    __syncthreads();
    double cnt = (double)N_ * Tn * Vn;
    double mean = s1 / cnt, var = s2 / cnt - mean * mean;
    double ersig = 1.0 / sqrt(var + 1e-5);
    double alpha = (double)eg[o] * ersig;
    double inv = 1.0 / cnt;
    double mu0 = tot[0] * inv, mu1 = tot[1] * inv, mu2 = tot[2] * inv;
    double c00 = tot[3] * inv - mu0 * mu0, c01 = tot[4] * inv - mu0 * mu1, c02 = tot[5] * inv - mu0 * mu2;
    double c11 = tot[6] * inv - mu1 * mu1, c12 = tot[7] * inv - mu1 * mu2, c22 = tot[8] * inv - mu2 * mu2;
    double w0 = edw[o * CIN + 0], w1 = edw[o * CIN + 1], w2 = edw[o * CIN + 2];
    double dmean = w0 * mu0 + w1 * mu1 + w2 * mu2 + (double)edb[o];
    double dvar = w0 * w0 * c00 + w1 * w1 * c11 + w2 * w2 * c22
                + 2.0 * (w0 * w1 * c01 + w0 * w2 * c02 + w1 * w2 * c12);
    double drsig = 1.0 / sqrt(dvar + 1e-5);
    double dga = (double)edg[o] * drsig;
    pcT[0 * 64 + o] = (float)alpha;
    pcT[1 * 64 + o] = (float)((double)ebt[o] - (double)eg[o] * mean * ersig
                              + dga * ((double)edb[o] - dmean) + (double)edbt[o]);
    pcT[2 * 64 + o] = (float)(dga * w0);
    pcT[3 * 64 + o] = (float)(dga * w1);
    pcT[4 * 64 + o] = (float)(dga * w2);
    pcT[5 * 64 + o] = 0.f;
}

/* dwd transpose */
__global__ __launch_bounds__(256)
void tr_dwd_kernel(const float* __restrict__ dwd, float* __restrict__ outp)
{
    int i = blockIdx.x * 256 + threadIdx.x;
    if (i < Kk * CE * CE) {
        int k = i / (CE * CE), r = i % (CE * CE);
        int o = r >> 6, c = r & 63;
        outp[((long)k * CE + c) * CE + o] = dwd[i];
    }
}

/* wa||wb transpose */
__global__ __launch_bounds__(256)
void tr_wab_kernel(const float* __restrict__ dwa, const float* __restrict__ dwb,
                   float* __restrict__ outp)
{
    int i = blockIdx.x * 256 + threadIdx.x;
    if (i < CE * 96) {
        int c = i / 96, j = i % 96;
        float v = (j < 48) ? dwa[j * CE + c] : dwb[(j - 48) * CE + c];
        outp[i] = v;
    }
}

/* penc helper for datt (ps stride 26, pad col zeroed) */
__device__ __forceinline__ void penc_tile(int tid, int NT, const float* xp,
    const float (*attE_s)[Vn][Vn], const float* ewd_s, const float (*pc_s)[6],
    float (*xs)[Vn], float* ez, float (*ps)[26])
{
    __syncthreads();
    for (int i = tid; i < CIN * Vn; i += NT) { int c = i / Vn, v = i % Vn; xs[c][v] = xp[c * TV + v]; }
    __syncthreads();
    for (int i = tid; i < Kk * CIN * Vn; i += NT) {
        int w = i % Vn, c = (i / Vn) % CIN, k = i / (Vn * CIN);
        float s = 0.f;
        #pragma unroll
        for (int v = 0; v < Vn; ++v) s += xs[c][v] * attE_s[k][v][w];
        ez[i] = s;
    }
    __syncthreads();
    for (int i = tid; i < CE * Vn; i += NT) {
        int w = i % Vn, o = i / Vn;
        float y = 0.f;
        #pragma unroll
        for (int k = 0; k < Kk; ++k)
            #pragma unroll
            for (int c = 0; c < CIN; ++c)
                y += ewd_s[(k * CE + o) * CIN + c] * ez[(k * CIN + c) * Vn + w];
        float val = pc_s[o][0] * y + pc_s[o][1]
                  + pc_s[o][2] * xs[0][w] + pc_s[o][3] * xs[1][w] + pc_s[o][4] * xs[2][w];
        ps[o][w] = fmaxf(val, 0.f);
    }
    for (int i = tid; i < CE; i += NT) ps[i][25] = 0.f;
    __syncthreads();
}

/* DEC ATT v2 — batched: grid 2*N*DSEG; partials to d_out scratch */
__global__ __launch_bounds__(512)
void datt_kernel(const float* __restrict__ x, const float* __restrict__ attEpB,
                 const float* __restrict__ ewd, const float* __restrict__ pcTB,
                 const float* __restrict__ wabTg,
                 const float* __restrict__ dba, const float* __restrict__ dbb,
                 float* __restrict__ attp)
{
    __shared__ float attE_s[Kk][Vn][Vn];
    __shared__ float ewd_s[Kk * CE * CIN];
    __shared__ float pc_s[CE][6];
    __shared__ float bias_s[96];
    __shared__ float xs[CIN][Vn];
    __shared__ float ez[Kk * CIN * Vn];
    __shared__ __align__(16) float ps[CE][26];
    __shared__ __align__(16) float fab[96][26];
    int b = blockIdx.x, s = b % DSEG, n = (b / DSEG) % N_, br = b / (DSEG * N_);
    const float* attEp = attEpB + (long)br * AEP_BR;
    const float* pcT = pcTB + br * 384;
    const float* xb = x + (long)br * (CIN * TV);
    int tid = threadIdx.x;
    for (int i = tid; i < Kk * VV; i += 512) {
        int k = i / 625, r = i - k * 625, v = r / 25, w = r - (r / 25) * 25;
        ((float*)attE_s)[i] = attEp[(long)n * 2100 + (k * 25 + v) * 28 + w];
    }
    for (int i = tid; i < Kk * CE * CIN; i += 512) ewd_s[i] = ewd[i];
    for (int i = tid; i < CE * 6; i += 512) pc_s[i & 63][i >> 6] = pcT[i];
    for (int i = tid; i < 96; i += 512) bias_s[i] = (i < 48) ? dba[i] : dbb[i - 48];

    int sk = tid / 169, sr = tid % 169;
    int sv0 = (sr / 13) * 2, sw0 = (sr % 13) * 2;
    float acc00 = 0.f, acc01 = 0.f, acc10 = 0.f, acc11 = 0.f;
    int fj0 = (tid / 13) * 4, fv0 = (tid % 13) * 2;

    const int TS = Tn / DSEG;
    for (int t = s * TS; t < s * TS + TS; ++t) {
        const float* xp = xb + (long)n * (Mn * CIN * TV) + t * Vn;
        penc_tile(tid, 512, xp, attE_s, ewd_s, pc_s, xs, ez, ps);
        if (tid < 312) {
            float ft[4][2] = {{0.f,0.f},{0.f,0.f},{0.f,0.f},{0.f,0.f}};
            const float* wg = wabTg + fj0;
            #pragma unroll 8
            for (int c = 0; c < 64; ++c) {
                f4 wv = *(const f4*)&wg[c * 96];
                f2 pv = *(const f2*)&ps[c][fv0];
                #pragma unroll
                for (int j = 0; j < 4; ++j) {
                    ft[j][0] += wv[j] * pv[0];
                    ft[j][1] += wv[j] * pv[1];
                }
            }
            #pragma unroll
            for (int j = 0; j < 4; ++j) {
                f2 r = { ft[j][0] + bias_s[fj0 + j], ft[j][1] + bias_s[fj0 + j] };
                *(f2*)&fab[fj0 + j][fv0] = r;
            }
        }
        __syncthreads();
        if (tid < 507) {
            #pragma unroll
            for (int i = 0; i < INTER_; ++i) {
                f2 a = *(const f2*)&fab[sk * INTER_ + i][sv0];
                f2 bb2 = *(const f2*)&fab[48 + sk * INTER_ + i][sw0];
                acc00 += a[0] * bb2[0]; acc01 += a[0] * bb2[1];
                acc10 += a[1] * bb2[0]; acc11 += a[1] * bb2[1];
            }
        }
    }
    if (tid < 507) {
        long ob = (((long)((br * N_ + n) * Kk + sk)) * DSEG + s) * VV;
        attp[ob + sv0 * 25 + sw0] = acc00;
        if (sw0 + 1 < 25)                 attp[ob + sv0 * 25 + sw0 + 1] = acc01;
        if (sv0 + 1 < 25)                 attp[ob + (sv0 + 1) * 25 + sw0] = acc10;
        if (sv0 + 1 < 25 && sw0 + 1 < 25) attp[ob + (sv0 + 1) * 25 + sw0 + 1] = acc11;
    }
}

/* =================================================================
 * DECY0: BN stats of raw dec-y — ONE BRANCH PER BLOCK (unchanged)
 * ================================================================= */
template<int TTC>
__global__ __launch_bounds__(128)
void decy0_kernel(const float* __restrict__ x,
                  const float* __restrict__ attEp,
                  const float* __restrict__ attDp,
                  const float* __restrict__ ewd,
                  const float* __restrict__ pcTg,
                  const float* __restrict__ dwdTg,
                  float* __restrict__ outp)
{
    constexpr int TBc = Tn / TTC;
    __shared__ __align__(16) float psT[25][68];
    __shared__ __align__(16) float dz_s[64][36];
    __shared__ __align__(16) float attD_s[Kk][25][32];
    __shared__ __align__(16) float ewdT_s[9][64];
    __shared__ __align__(16) float ez_s[9][28];
    __shared__ float xs[3][25];

    int b = blockIdx.x;
    int br = b / (N_ * TBc);
    int rem = b - br * (N_ * TBc);
    int n = rem / TBc, tb = rem - (rem / TBc) * TBc;
    int tid = threadIdx.x;
    int tq = tid >> 3, tw8 = tid & 7;
    int q0 = tq * 4, w0 = tw8 * 4;

    for (int i = tid; i < 576; i += 128) {
        int kc = i >> 6, o = i & 63;
        int k = kc / 3, c = kc - k * 3;
        ewdT_s[kc][o] = ewd[(k * 64 + o) * 3 + c];
    }
    for (int i = tid; i < 600; i += 128) {
        int r = i * 4;
        *(f4*)&((float*)attD_s)[r] = *(const f4*)&attDp[(long)br * ADP_BR + n * 2400 + r];
    }

    float s1_[4] = {0.f,0.f,0.f,0.f}, s2_[4] = {0.f,0.f,0.f,0.f};

    for (int tt = 0; tt < TTC; ++tt) {
        int t = tb * TTC + tt;
        __syncthreads();
        for (int i = tid; i < 75; i += 128) {
            int c = i / 25, v = i - (i / 25) * 25;
            xs[c][v] = x[(long)br * (CIN * TV) + (long)n * (Mn * CIN * TV)
                         + c * TV + t * 25 + v];
        }
        __syncthreads();
        if (tid < 72) {
            int kc = tid >> 3, wg = tid & 7;
            if (wg < 7) {
                int k = kc / 3, c = kc - k * 3;
                const float* aE = attEp + (long)br * AEP_BR + n * 2100 + k * 700;
                float e0 = 0.f, e1 = 0.f, e2 = 0.f, e3 = 0.f;
                #pragma unroll
                for (int v = 0; v < 25; ++v) {
                    f4 ae = *(const f4*)&aE[v * 28 + wg * 4];
                    float xv = xs[c][v];
                    e0 += xv * ae[0]; e1 += xv * ae[1];
                    e2 += xv * ae[2]; e3 += xv * ae[3];
                }
                f4 r = { e0, e1, e2, e3 };
                *(f4*)&ez_s[kc][wg * 4] = r;
            }
        }
        __syncthreads();
        for (int g = tid; g < 400; g += 128) {
            int og = (g & 15) << 2, w = g >> 4;
            float y0 = 0.f, y1 = 0.f, y2 = 0.f, y3 = 0.f;
            #pragma unroll
            for (int kc = 0; kc < 9; ++kc) {
                f4 wt = *(const f4*)&ewdT_s[kc][og];
                float ev = ez_s[kc][w];
                y0 += wt[0] * ev; y1 += wt[1] * ev;
                y2 += wt[2] * ev; y3 += wt[3] * ev;
            }
            const float* pcb = pcTg + br * 384;
            f4 al = *(const f4*)&pcb[0 * 64 + og];
            f4 be = *(const f4*)&pcb[1 * 64 + og];
            f4 d0 = *(const f4*)&pcb[2 * 64 + og];
            f4 d1 = *(const f4*)&pcb[3 * 64 + og];
            f4 d2 = *(const f4*)&pcb[4 * 64 + og];
            float x0 = xs[0][w], x1 = xs[1][w], x2 = xs[2][w];
            f4 r;
            r[0] = fmaxf(al[0] * y0 + be[0] + d0[0] * x0 + d1[0] * x1 + d2[0] * x2, 0.f);
            r[1] = fmaxf(al[1] * y1 + be[1] + d0[1] * x0 + d1[1] * x1 + d2[1] * x2, 0.f);
            r[2] = fmaxf(al[2] * y2 + be[2] + d0[2] * x0 + d1[2] * x1 + d2[2] * x2, 0.f);
            r[3] = fmaxf(al[3] * y3 + be[3] + d0[3] * x0 + d1[3] * x1 + d2[3] * x2, 0.f);
            *(f4*)&psT[w][og] = r;
        }
        float acc[4][4];
        #pragma unroll
        for (int j = 0; j < 4; ++j)
            #pragma unroll
            for (int m = 0; m < 4; ++m) acc[j][m] = 0.f;
        for (int k = 0; k < Kk; ++k) {
            __syncthreads();
            {
                float dzt[4][4];
                #pragma unroll
                for (int j = 0; j < 4; ++j)
                    #pragma unroll
                    for (int m = 0; m < 4; ++m) dzt[j][m] = 0.f;
                for (int v = 0; v < 25; ++v) {
                    f4 pa = *(const f4*)&psT[v][q0];
                    f4 ad = *(const f4*)&attD_s[k][v][w0];
                    #pragma unroll
                    for (int j = 0; j < 4; ++j)
                        #pragma unroll
                        for (int m = 0; m < 4; ++m) dzt[j][m] += pa[j] * ad[m];
                }
                #pragma unroll
                for (int j = 0; j < 4; ++j) {
                    f4 wv = { dzt[j][0], dzt[j][1], dzt[j][2], dzt[j][3] };
                    *(f4*)&dz_s[q0 + j][w0] = wv;
                }
            }
            __syncthreads();
            const float* wgp = dwdTg + k * 4096 + q0;
            #pragma unroll 8
            for (int c = 0; c < 64; ++c) {
                f4 wv = *(const f4*)&wgp[c * 64];
                f4 zv = *(const f4*)&dz_s[c][w0];
                #pragma unroll
                for (int j = 0; j < 4; ++j)
                    #pragma unroll
                    for (int m = 0; m < 4; ++m) acc[j][m] += wv[j] * zv[m];
            }
        }
        #pragma unroll
        for (int m = 0; m < 4; ++m) if (w0 + m < 25)
            #pragma unroll
            for (int j = 0; j < 4; ++j) {
                float a = acc[j][m]; s1_[j] += a; s2_[j] += a * a;
            }
    }
    float* red = (float*)dz_s;
    #pragma unroll
    for (int pass = 0; pass < 2; ++pass) {
        __syncthreads();
        #pragma unroll
        for (int j = 0; j < 4; ++j)
            red[(q0 + j) * 8 + tw8] = pass ? s2_[j] : s1_[j];
        __syncthreads();
        if (tid < 64) {
            float a = 0.f;
            #pragma unroll
            for (int q = 0; q < 8; ++q) a += red[tid * 8 + q];
            long pb = (((long)br * N_ + n) * TBc + tb) * 128;
            outp[pb + tid * 2 + pass] = a;
        }
    }
}

/* =================================================================
 * DECY1 v4: round-14/16 schedule, but 256 THREADS on the SAME LDS
 * (51.2KB -> 3 blocks/CU preserved): dz/dy 4x2 per-thread tiles
 * (work halved), 12 waves/CU (was 6). Sequential u-loop.
 * ================================================================= */
template<int TTC>
__global__ __launch_bounds__(256)
void decy1_kernel(const float* __restrict__ x,
                  const float* __restrict__ attEp,
                  const float* __restrict__ attDp,
                  const float* __restrict__ ewd,
                  const float* __restrict__ pcTg,
                  const float* __restrict__ ycb,
                  const float* __restrict__ dwdTg,
                  float* __restrict__ outp)
{
    constexpr int TBc = Tn / TTC;
    __shared__ __align__(16) float psT[2][25][68];
    __shared__ __align__(16) float dz_s[64][36];
    __shared__ __align__(16) float attD_s[2][Kk][25][32];
    __shared__ __align__(16) float ewdT_s[9][64];
    __shared__ __align__(16) float ez_s[2][9][28];
    __shared__ __align__(16) float pcT_s[2][6][64];
    __shared__ __align__(16) float yc_s[2][64][2];
    __shared__ float xs[2][3][25];

    int b = blockIdx.x, tb = b % TBc, n = b / TBc;
    int tid = threadIdx.x;
    int tq = tid >> 4;                 /* 0..15: o-quad */
    int tw16 = tid & 15;               /* 0..15: w-pair */
    int q0 = tq * 4, w0 = tw16 * 2;    /* w0 in {0..30}; cols 25..31 zero-pad */

    for (int i = tid; i < 576; i += 256) {
        int kc = i >> 6, o = i & 63;
        int k = kc / 3, c = kc - k * 3;
        ewdT_s[kc][o] = ewd[(k * 64 + o) * 3 + c];
    }
    for (int i = tid; i < 1200; i += 256) {
        int u2 = i / 600, r = (i - u2 * 600) * 4;
        *(f4*)&((float*)attD_s)[u2 * 2400 + r] =
            *(const f4*)&attDp[(long)u2 * ADP_BR + n * 2400 + r];
    }
    for (int i = tid; i < 768; i += 256) ((float*)pcT_s)[i] = pcTg[i];
    for (int i = tid; i < 256; i += 256) ((float*)yc_s)[i] = ycb[i];

    for (int tt = 0; tt < TTC; ++tt) {
        int t = tb * TTC + tt;
        __syncthreads();   /* staging / prev rr readers done */
        for (int i = tid; i < 150; i += 256) {
            int uu = i / 75, r = i - uu * 75, c = r / 25, v = r - (r / 25) * 25;
            xs[uu][c][v] = x[(((long)n * 2 + uu) * 3 + c) * TV + t * 25 + v];
        }
        __syncthreads();
        if (tid < 144) {
            int u2 = tid >= 72; int gg = tid - u2 * 72;
            int kc = gg >> 3, wg = gg & 7;
            if (wg < 7) {
                int k = kc / 3, c = kc - k * 3;
                const float* aE = attEp + u2 * AEP_BR + n * 2100 + k * 700;
                float e0 = 0.f, e1 = 0.f, e2 = 0.f, e3 = 0.f;
                #pragma unroll
                for (int v = 0; v < 25; ++v) {
                    f4 ae = *(const f4*)&aE[v * 28 + wg * 4];
                    float xv = xs[u2][c][v];
                    e0 += xv * ae[0]; e1 += xv * ae[1];
                    e2 += xv * ae[2]; e3 += xv * ae[3];
                }
                f4 r = { e0, e1, e2, e3 };
                *(f4*)&ez_s[u2][kc][wg * 4] = r;
            }
        }
        __syncthreads();
        for (int g = tid; g < 800; g += 256) {
            int u2 = g >= 400; int gg = g - u2 * 400;
            int og = (gg & 15) << 2, w = gg >> 4;
            float y0 = 0.f, y1 = 0.f, y2 = 0.f, y3 = 0.f;
            #pragma unroll
            for (int kc = 0; kc < 9; ++kc) {
                f4 wt = *(const f4*)&ewdT_s[kc][og];
                float ev = ez_s[u2][kc][w];
                y0 += wt[0] * ev; y1 += wt[1] * ev;
                y2 += wt[2] * ev; y3 += wt[3] * ev;
            }
            const float* pcb = &pcT_s[u2][0][0];
            f4 al = *(const f4*)&pcb[0 * 64 + og];
            f4 be = *(const f4*)&pcb[1 * 64 + og];
            f4 d0 = *(const f4*)&pcb[2 * 64 + og];
            f4 d1 = *(const f4*)&pcb[3 * 64 + og];
            f4 d2 = *(const f4*)&pcb[4 * 64 + og];
            float x0 = xs[u2][0][w], x1 = xs[u2][1][w], x2 = xs[u2][2][w];
            f4 r;
            r[0] = fmaxf(al[0] * y0 + be[0] + d0[0] * x0 + d1[0] * x1 + d2[0] * x2, 0.f);
            r[1] = fmaxf(al[1] * y1 + be[1] + d0[1] * x0 + d1[1] * x1 + d2[1] * x2, 0.f);
            r[2] = fmaxf(al[2] * y2 + be[2] + d0[2] * x0 + d1[2] * x1 + d2[2] * x2, 0.f);
            r[3] = fmaxf(al[3] * y3 + be[3] + d0[3] * x0 + d1[3] * x1 + d2[3] * x2, 0.f);
            *(f4*)&psT[u2][w][og] = r;
        }
        for (int u2 = 0; u2 < 2; ++u2) {
            float acc[4][2] = {{0.f,0.f},{0.f,0.f},{0.f,0.f},{0.f,0.f}};
            for (int k = 0; k < Kk; ++k) {
                __syncthreads();   /* psT ready / prev dy readers of dz_s done */
                {
                    float dzt[4][2] = {{0.f,0.f},{0.f,0.f},{0.f,0.f},{0.f,0.f}};
                    for (int v = 0; v < 25; ++v) {
                        f4 pa = *(const f4*)&psT[u2][v][q0];
                        f2 ad = *(const f2*)&attD_s[u2][k][v][w0];
                        #pragma unroll
                        for (int j = 0; j < 4; ++j) {
                            dzt[j][0] += pa[j] * ad[0];
                            dzt[j][1] += pa[j] * ad[1];
                        }
                    }
                    #pragma unroll
                    for (int j = 0; j < 4; ++j) {
                        f2 wv = { dzt[j][0], dzt[j][1] };
                        *(f2*)&dz_s[q0 + j][w0] = wv;
                    }
                }
                __syncthreads();
                const float* wgp = dwdTg + k * 4096 + q0;
                #pragma unroll 8
                for (int c = 0; c < 64; ++c) {
                    f4 wv = *(const f4*)&wgp[c * 64];
                    f2 zv = *(const f2*)&dz_s[c][w0];
                    #pragma unroll
                    for (int j = 0; j < 4; ++j) {
                        acc[j][0] += wv[j] * zv[0];
                        acc[j][1] += wv[j] * zv[1];
                    }
                }
            }
            const float* ycu = &yc_s[u2][0][0];
            #pragma unroll
            for (int m = 0; m < 2; ++m) {
                int w = w0 + m;
                if (w < 25) {
                    #pragma unroll
                    for (int j = 0; j < 4; ++j) {
                        float pd = ycu[(q0 + j) * 2] * acc[j][m]
                                 + ycu[(q0 + j) * 2 + 1] + psT[u2][w][q0 + j];
                        psT[u2][w][q0 + j] = fmaxf(pd, 0.f);
                    }
                }
            }
        }
        __syncthreads();   /* all pd written */
        if (tid < 169) {
            int tv = tid / 13, tw2 = tid % 13;
            int v0 = tv * 2, ww0 = tw2 * 2;
            float r00 = 0.f, r01 = 0.f, r10 = 0.f, r11 = 0.f;
            for (int c = 0; c < 64; c += 4) {
                f4 a0 = *(const f4*)&psT[0][v0][c];
                f4 a1 = *(const f4*)&psT[0][v0 + 1][c];
                f4 b0 = *(const f4*)&psT[1][ww0][c];
                f4 b1 = *(const f4*)&psT[1][ww0 + 1][c];
                #pragma unroll
                for (int q = 0; q < 4; ++q) {
                    r00 += a0[q] * b0[q]; r01 += a0[q] * b1[q];
                    r10 += a1[q] * b0[q]; r11 += a1[q] * b1[q];
                }
            }
            long ob = ((long)n * Tn + t) * VV;
            outp[ob + v0 * 25 + ww0] = r00;
            if (ww0 + 1 < 25)                outp[ob + v0 * 25 + ww0 + 1] = r01;
            if (v0 + 1 < 25)                 outp[ob + (v0 + 1) * 25 + ww0] = r10;
            if (v0 + 1 < 25 && ww0 + 1 < 25) outp[ob + (v0 + 1) * 25 + ww0 + 1] = r11;
        }
    }
}

/* DEC finalize — batched: 2 blocks (one per branch) */
__global__ __launch_bounds__(64)
void dec_fin_kernel(const float* __restrict__ partB, int nparts,
                    const float* __restrict__ dg, const float* __restrict__ dbt,
                    float* __restrict__ ycB)
{
    int br = blockIdx.x;
    const float* part = partB + (long)br * nparts * 128;
    float* yc = ycB + br * 128;
    int o = threadIdx.x;
    double s1 = 0, s2 = 0;
    for (int b = 0; b < nparts; ++b) { s1 += part[(long)b * 128 + o * 2]; s2 += part[(long)b * 128 + o * 2 + 1]; }
    double cnt = (double)N_ * Tn * Vn;
    double mean = s1 / cnt, var = s2 / cnt - mean * mean;
    double rsig = 1.0 / sqrt(var + 1e-5);
    double a = (double)dg[o] * rsig;
    yc[o * 2 + 0] = (float)a;
    yc[o * 2 + 1] = (float)((double)dbt[o] - a * mean);
}

/* BN stats over (n,v,w) per t */
__global__ __launch_bounds__(256)
void rrbn_kernel(const float* __restrict__ rr, float* __restrict__ tstats)
{
    int t = blockIdx.x;
    double s = 0.0, s2 = 0.0;
    for (int idx = threadIdx.x; idx < N_ * VV; idx += 256) {
        int n = idx / VV, j = idx % VV;
        float v = rr[((long)n * Tn + t) * VV + j];
        s += v; s2 += (double)v * v;
    }
    __shared__ double rs[256], rs2[256];
    int tid = threadIdx.x;
    rs[tid] = s; rs2[tid] = s2;
    __syncthreads();
    for (int off = 128; off > 0; off >>= 1) {
        if (tid < off) { rs[tid] += rs[tid + off]; rs2[tid] += rs2[tid + off]; }
        __syncthreads();
    }
    if (tid == 0) {
        double cnt = (double)N_ * VV;
        double mean = rs[0] / cnt;
        double var = rs2[0] / cnt - mean * mean;
        tstats[t * 2 + 0] = (float)mean;
        tstats[t * 2 + 1] = (float)(1.0 / sqrt(var + 1e-5));
    }
}

/* FINAL */
__global__ __launch_bounds__(128)
void final_kernel(const float* __restrict__ tstats,
                  const float* __restrict__ x, const float* __restrict__ iparam,
                  const float* __restrict__ tgamma, const float* __restrict__ tbeta,
                  float* out)
{
    int b = blockIdx.x;
    int t = b % Tn, n = b / Tn;
    __shared__ float xa_s[CIN][Vn], xb_s[CIN][Vn];
    __shared__ float ram_s[VV];
    __shared__ float da_s[Vn], db_s[Vn];
    __shared__ float varc[CIN];
    __shared__ float abf;
    int tid = threadIdx.x;

    for (int idx = tid; idx < 2 * CIN * Vn; idx += 128) {
        int half = idx / (CIN * Vn);
        int r = idx % (CIN * Vn);
        int c = r / Vn, v = r % Vn;
        float val = x[(((long)n * Mn + half) * CIN + c) * TV + t * Vn + v];
        if (half == 0) xa_s[c][v] = val; else xb_s[c][v] = val;
    }
    __syncthreads();
    if (tid < CIN) {
        float s = 0.f, s2 = 0.f;
        #pragma unroll
        for (int v = 0; v < Vn; ++v) { float q = xb_s[tid][v]; s += q; s2 += q * q; }
        float mean = s / Vn;
        varc[tid] = (s2 - Vn * mean * mean) / (Vn - 1);
    }
    __syncthreads();
    if (tid == 0) {
        float absum = varc[0] + varc[1] + varc[2];
        abf = (absum < 1e-4f) ? 0.f : 1.f;
    }
    float pct = 0.5f * (tanhf(iparam[0]) + 1.f);
    float mt = tstats[t * 2], rt = tstats[t * 2 + 1];
    float gt = tgamma[t], bt = tbeta[t];
    __syncthreads();

    for (int idx = tid; idx < VV; idx += 128) {
        int v = idx / Vn, w = idx % Vn;
        float rrv = out[(long)b * VV + idx];
        float rbn = gt * (rrv - mt) * rt + bt;
        float ramr = 0.5f * (tanhf(rbn) + 1.f);
        float gsum = 0.f;
        #pragma unroll
        for (int c = 0; c < CIN; ++c) {
            float d = expf(xa_s[c][v]) * expf(-xb_s[c][w]);
            float l = logf(d + 1e-5f);
            gsum += l * l;
        }
        float ramg = expf(-(1.f / 3.f) * gsum);
        float ram = pct * ramr + (1.f - pct) * ramg;
        ram *= abf;
        if (ram < 0.5f) ram = 0.f;
        ram_s[idx] = ram;
    }
    __syncthreads();
    if (tid < Vn) {
        float s = 0.f;
        #pragma unroll
        for (int v = 0; v < Vn; ++v) s += ram_s[v * Vn + tid];
        da_s[tid] = s;
    } else if (tid >= 64 && tid < 64 + Vn) {
        int v = tid - 64;
        float s = 0.f;
        #pragma unroll
        for (int w = 0; w < Vn; ++w) s += ram_s[v * Vn + w];
        db_s[v] = s;
    }
    __syncthreads();
    for (int idx = tid; idx < VV; idx += 128) {
        int v = idx / Vn, w = idx % Vn;
        float ram = ram_s[idx];
        out[(long)b * VV + idx] = ram * rsqrtf(db_s[v] * da_s[w] + 1e-5f);
    }
}

/* ================================================================= */
extern "C" void kernel_launch(void* const* d_in, const int* in_sizes, int n_in,
                              void* d_out, int out_size, void* d_ws, size_t ws_size,
                              hipStream_t stream)
{
    const float* x    = (const float*)d_in[0];
    const float* A    = (const float*)d_in[1];
    const float* ip   = (const float*)d_in[2];
    const float* rg   = (const float*)d_in[3];
    const float* rbta = (const float*)d_in[4];
    const float* ePA  = (const float*)d_in[5];
    const float* ewa  = (const float*)d_in[6];
    const float* eba  = (const float*)d_in[7];
    const float* ewb  = (const float*)d_in[8];
    const float* ebb  = (const float*)d_in[9];
    const float* ewd  = (const float*)d_in[10];
    const float* ebd  = (const float*)d_in[11];  (void)ebd;
    const float* eg   = (const float*)d_in[12];
    const float* ebt  = (const float*)d_in[13];
    const float* edw  = (const float*)d_in[14];
    const float* edb  = (const float*)d_in[15];
    const float* edg  = (const float*)d_in[16];
    const float* edbt = (const float*)d_in[17];
    const float* dPA  = (const float*)d_in[18];
    const float* dwa  = (const float*)d_in[19];
    const float* dba  = (const float*)d_in[20];
    const float* dwb  = (const float*)d_in[21];
    const float* dbb  = (const float*)d_in[22];
    const float* dwd  = (const float*)d_in[23];
    const float* dbd  = (const float*)d_in[24];  (void)dbd;
    const float* dg   = (const float*)d_in[25];
    const float* dbt  = (const float*)d_in[26];

    if (ws_size < (size_t)WS_REQ * sizeof(float)) return;

    float* ws    = (float*)d_ws;
    float* attp  = ws + OFF_ATTP;
    float* part  = ws + OFF_PART;
    float* attEp = ws + OFF_ATTEP;
    float* attDp = ws + OFF_ATTDP;
    double* covp = (double*)(ws + OFF_COV);
    float* pcT   = ws + OFF_PCT;
    float* yc    = ws + OFF_YC;
    float* tst   = ws + OFF_TST;
    float* dwdTg = ws + OFF_DWDT;
    float* wabTg = ws + OFF_WABT;
    float* outf  = (float*)d_out;

    tr_dwd_kernel<<<(Kk * CE * CE + 255) / 256, 256, 0, stream>>>(dwd, dwdTg);
    tr_wab_kernel<<<(CE * 96 + 255) / 256, 256, 0, stream>>>(dwa, dwb, wabTg);

    /* -------- both branches batched per dispatch -------- */
    att_kernel<<<2 * N_ * Kk * ESEG, 640, 0, stream>>>(
        x, ewa, eba, ewb, ebb, attp);
    softmax_kernel<ESEG, 28><<<2 * N_ * Kk, 256, 0, stream>>>(attp, A, ePA, attEp);
    xcov_kernel<<<240, 256, 0, stream>>>(x, covp);
    ey_stat_kernel<<<2 * N_ * EYB, 256, 0, stream>>>(x, attEp, ewd, part);
    enc_fin_kernel<<<2, 64, 0, stream>>>(part, covp, eg, ebt, edw, edb, edg, edbt, pcT);
    /* datt partials use d_out as scratch (dead until decy1 overwrites) */
    datt_kernel<<<2 * N_ * DSEG, 512, 0, stream>>>(
        x, attEp, ewd, pcT, wabTg, dba, dbb, outf);
    softmax_kernel<DSEG, 32><<<2 * N_ * Kk, 256, 0, stream>>>(outf, A, dPA, attDp);

    /* dec-y stats: one branch per block, TTC=5 -> 7680 blocks */
    decy0_kernel<5><<<2 * N_ * (Tn / 5), 128, 0, stream>>>(
        x, attEp, attDp, ewd, pcT, dwdTg, part);
    dec_fin_kernel<<<2, 64, 0, stream>>>(part, N_ * (Tn / 5), dg, dbt, yc);
    /* full dec out + rr: 256 threads, same LDS (3 blocks/CU), TTC=2 */
    decy1_kernel<2><<<N_ * (Tn / 2), 256, 0, stream>>>(
        x, attEp, attDp, ewd, pcT, yc, dwdTg, outf);

    rrbn_kernel<<<Tn, 256, 0, stream>>>(outf, tst);
    final_kernel<<<N_ * Tn, 128, 0, stream>>>(tst, x, ip, rg, rbta, outf);
}

// Round 18
// 3826.796 us; speedup vs baseline: 1.1565x; 1.1565x over previous
//
#include <hip/hip_runtime.h>
#include <math.h>

#define N_     64
#define Mn     2
#define Tn     300
#define Vn     25
#define Kk     3
#define CIN    3
#define CE     64
#define INTER_ 16
#define TV     7500
#define VV     625
#define ESEG   5      /* enc att t-segments (60 t each) */
#define DSEG   15     /* dec att t-segments (20 t each) */
#define EYB    12     /* ey_stat t-blocks (25 t each) */

typedef float f4 __attribute__((ext_vector_type(4)));
typedef float f2 __attribute__((ext_vector_type(2)));

/* ---------------- workspace layout (float offsets) ----------------
 * region0: att partials 2*N*K*ESEG*VV = 1,200,000 (exactly) ;
 *          decy0 partials 2*N*60*128 = 983,040.
 * datt partials (2*N*K*DSEG*VV = 3.6M) live in d_out (dead until decy1). */
#define OFF_ATTP  0L
#define OFF_PART  0L
#define OFF_ATTEP 1200000L   /* [2] 268,800 */
#define OFF_ATTDP 1468800L   /* [2] 307,200 */
#define OFF_COV   1776000L   /* doubles: 2*120*9 -> 4320 floats */
#define OFF_PCT   1780320L   /* [2][6][64] = 768 */
#define OFF_YC    1781088L   /* 256 */
#define OFF_TST   1781344L   /* 600 */
#define OFF_DWDT  1781944L   /* 12288 */
#define OFF_WABT  1794232L   /* 6144 */
#define WS_REQ    1800376L

#define AEP_BR 134400   /* attEp branch stride (floats) */
#define ADP_BR 153600   /* attDp branch stride */

/* =================================================================
 * ENC ATT partials — batched over branches
 * ================================================================= */
__global__ __launch_bounds__(640)
void att_kernel(const float* __restrict__ x,
                const float* __restrict__ wa, const float* __restrict__ ba,
                const float* __restrict__ wb, const float* __restrict__ bb,
                float* __restrict__ att_partial)
{
    int b = blockIdx.x;
    int s = b % ESEG;
    int k = (b / ESEG) % Kk;
    int n = (b / (ESEG * Kk)) % N_;
    int br = b / (ESEG * Kk * N_);
    const float* xp = x + (long)br * (CIN * TV) + (long)n * (Mn * CIN * TV);

    __shared__ float xs[CIN][Vn];
    __shared__ float fa_s[INTER_][Vn];
    __shared__ float fb_s[INTER_][Vn];

    int tid = threadIdx.x;
    float acc = 0.f;
    const int TSEG = Tn / ESEG;
    int t0 = s * TSEG;
    for (int t = t0; t < t0 + TSEG; ++t) {
        __syncthreads();
        for (int idx = tid; idx < CIN * Vn; idx += 640) {
            int c = idx / Vn, v = idx % Vn;
            xs[c][v] = xp[(long)c * TV + t * Vn + v];
        }
        __syncthreads();
        for (int idx = tid; idx < 2 * INTER_ * Vn; idx += 640) {
            int j = idx;
            const float* w; const float* bias; float (*dst)[Vn];
            if (j < INTER_ * Vn) { w = wa; bias = ba; dst = fa_s; }
            else { j -= INTER_ * Vn; w = wb; bias = bb; dst = fb_s; }
            int i = j / Vn, v = j % Vn;
            float sum = bias[k * INTER_ + i];
            const float* wr = w + (k * INTER_ + i) * CIN;
            #pragma unroll
            for (int c = 0; c < CIN; ++c) sum += wr[c] * xs[c][v];
            dst[i][v] = sum;
        }
        __syncthreads();
        if (tid < VV) {
            int v = tid / Vn, w = tid % Vn;
            float a = 0.f;
            #pragma unroll
            for (int i = 0; i < INTER_; ++i) a += fa_s[i][v] * fb_s[i][w];
            acc += a;
        }
    }
    if (tid < VV)
        att_partial[(((long)((br * N_ + n) * Kk + k)) * ESEG + s) * VV + tid] = acc;
}

/* softmax over v per (br,n,k,w), then + (A+PA); writes PADDED layout. */
template<int SEGS, int PADW>
__global__ __launch_bounds__(256)
void softmax_kernel(const float* __restrict__ att_partial,
                    const float* __restrict__ A, const float* __restrict__ PA,
                    float* __restrict__ attP)
{
    int b = blockIdx.x;
    int k = b % Kk;
    __shared__ float as[VV];
    int tid = threadIdx.x;
    for (int idx = tid; idx < VV; idx += 256) {
        float s = 0.f;
        for (int seg = 0; seg < SEGS; ++seg)
            s += att_partial[((long)b * SEGS + seg) * VV + idx];
        as[idx] = s * (1.0f / (INTER_ * Tn));
    }
    __syncthreads();
    if (tid < Vn) {
        int w = tid;
        float m = -1e30f;
        #pragma unroll
        for (int v = 0; v < Vn; ++v) m = fmaxf(m, as[v * Vn + w]);
        float e[Vn];
        float den = 0.f;
        #pragma unroll
        for (int v = 0; v < Vn; ++v) { e[v] = expf(as[v * Vn + w] - m); den += e[v]; }
        float inv = 1.f / den;
        #pragma unroll
        for (int v = 0; v < Vn; ++v)
            attP[((long)b * Vn + v) * PADW + w] =
                e[v] * inv + A[k * VV + v * Vn + w] + PA[k * VV + v * Vn + w];
    } else if (tid < PADW) {
        #pragma unroll
        for (int v = 0; v < Vn; ++v)
            attP[((long)b * Vn + v) * PADW + tid] = 0.f;
    }
}

/* x covariance partials — batched: grid 240, 120 per branch */
__global__ __launch_bounds__(256)
void xcov_kernel(const float* __restrict__ x, double* __restrict__ part)
{
    int br = blockIdx.x / 120, g = blockIdx.x % 120;
    const float* xbase = x + (long)br * (CIN * TV);
    double a[9];
    #pragma unroll
    for (int q = 0; q < 9; ++q) a[q] = 0.0;
    for (long idx = (long)g * 256 + threadIdx.x; idx < (long)N_ * TV;
         idx += 120L * 256) {
        int n = (int)(idx / TV);
        int j = (int)(idx % TV);
        const float* xp = xbase + (long)n * (Mn * CIN * TV) + j;
        float x0 = xp[0], x1 = xp[TV], x2 = xp[2 * TV];
        a[0] += x0; a[1] += x1; a[2] += x2;
        a[3] += (double)x0 * x0; a[4] += (double)x0 * x1; a[5] += (double)x0 * x2;
        a[6] += (double)x1 * x1; a[7] += (double)x1 * x2; a[8] += (double)x2 * x2;
    }
    __shared__ double red[256];
    int tid = threadIdx.x;
    for (int q = 0; q < 9; ++q) {
        red[tid] = a[q];
        __syncthreads();
        for (int off = 128; off > 0; off >>= 1) {
            if (tid < off) red[tid] += red[tid + off];
            __syncthreads();
        }
        if (tid == 0) part[(long)blockIdx.x * 9 + q] = red[0];
        __syncthreads();
    }
}

/* ENC y stats — batched: grid 2*N*EYB */
__global__ __launch_bounds__(256)
void ey_stat_kernel(const float* __restrict__ x, const float* __restrict__ attEpB,
                    const float* __restrict__ ewd, float* __restrict__ part)
{
    __shared__ float attE_s[Kk][Vn][Vn];
    __shared__ float ewd_s[Kk * CE * CIN];
    __shared__ float xs[CIN][Vn];
    __shared__ float ez[Kk * CIN * Vn];
    __shared__ float ys[CE][Vn];
    int b = blockIdx.x, tb = b % EYB, n = (b / EYB) % N_, br = b / (EYB * N_);
    const float* attEp = attEpB + (long)br * AEP_BR;
    const float* xb = x + (long)br * (CIN * TV);
    int tid = threadIdx.x;
    for (int i = tid; i < Kk * VV; i += 256) {
        int k = i / 625, r = i - k * 625, v = r / 25, w = r - (r / 25) * 25;
        ((float*)attE_s)[i] = attEp[(long)n * 2100 + (k * 25 + v) * 28 + w];
    }
    for (int i = tid; i < Kk * CE * CIN; i += 256) ewd_s[i] = ewd[i];
    float s1 = 0.f, s2 = 0.f;
    for (int t = tb * 25; t < tb * 25 + 25; ++t) {
        const float* xp = xb + (long)n * (Mn * CIN * TV) + t * Vn;
        __syncthreads();
        for (int i = tid; i < CIN * Vn; i += 256) { int c = i / Vn, v = i % Vn; xs[c][v] = xp[c * TV + v]; }
        __syncthreads();
        for (int i = tid; i < Kk * CIN * Vn; i += 256) {
            int w = i % Vn, c = (i / Vn) % CIN, k = i / (Vn * CIN);
            float s = 0.f;
            #pragma unroll
            for (int v = 0; v < Vn; ++v) s += xs[c][v] * attE_s[k][v][w];
            ez[i] = s;
        }
        __syncthreads();
        for (int i = tid; i < CE * Vn; i += 256) {
            int w = i % Vn, o = i / Vn;
            float y = 0.f;
            #pragma unroll
            for (int k = 0; k < Kk; ++k)
                #pragma unroll
                for (int c = 0; c < CIN; ++c)
                    y += ewd_s[(k * CE + o) * CIN + c] * ez[(k * CIN + c) * Vn + w];
            ys[o][w] = y;
        }
        __syncthreads();
        if (tid < CE) {
            #pragma unroll
            for (int w = 0; w < Vn; ++w) { float y = ys[tid][w]; s1 += y; s2 += y * y; }
        }
    }
    if (tid < CE) { part[(long)b * 128 + tid * 2] = s1; part[(long)b * 128 + tid * 2 + 1] = s2; }
}

/* ENC finalize — batched: 2 blocks (one per branch) */
__global__ __launch_bounds__(64)
void enc_fin_kernel(const float* __restrict__ partB,
                    const double* __restrict__ covpB,
                    const float* __restrict__ eg, const float* __restrict__ ebt,
                    const float* __restrict__ edw, const float* __restrict__ edb,
                    const float* __restrict__ edg, const float* __restrict__ edbt,
                    float* __restrict__ pcTB)
{
    int br = blockIdx.x;
    const float* part = partB + (long)br * (N_ * EYB * 128);
    const double* covp = covpB + (long)br * (120 * 9);
    float* pcT = pcTB + br * 384;
    int o = threadIdx.x;
    __shared__ double tot[9];
    if (o < 9) { double s = 0; for (int g = 0; g < 120; ++g) s += covp[(long)g * 9 + o]; tot[o] = s; }
    double s1 = 0, s2 = 0;
    for (int b = 0; b < N_ * EYB; ++b) { s1 += part[(long)b * 128 + o * 2]; s2 += part[(long)b * 128 + o * 2 + 1]; }
    __syncthreads();
    double cnt = (double)N_ * Tn * Vn;
    double mean = s1 / cnt, var = s2 / cnt - mean * mean;
    double ersig = 1.0 / sqrt(var + 1e-5);
    double alpha = (double)eg[o] * ersig;
    double inv = 1.0 / cnt;
    double mu0 = tot[0] * inv, mu1 = tot[1] * inv, mu2 = tot[2] * inv;
    double c00 = tot[3] * inv - mu0 * mu0, c01 = tot[4] * inv - mu0 * mu1, c02 = tot[5] * inv - mu0 * mu2;
    double c11 = tot[6] * inv - mu1 * mu1, c12 = tot[7] * inv - mu1 * mu2, c22 = tot[8] * inv - mu2 * mu2;
    double w0 = edw[o * CIN + 0], w1 = edw[o * CIN + 1], w2 = edw[o * CIN + 2];
    double dmean = w0 * mu0 + w1 * mu1 + w2 * mu2 + (double)edb[o];
    double dvar = w0 * w0 * c00 + w1 * w1 * c11 + w2 * w2 * c22
                + 2.0 * (w0 * w1 * c01 + w0 * w2 * c02 + w1 * w2 * c12);
    double drsig = 1.0 / sqrt(dvar + 1e-5);
    double dga = (double)edg[o] * drsig;
    pcT[0 * 64 + o] = (float)alpha;
    pcT[1 * 64 + o] = (float)((double)ebt[o] - (double)eg[o] * mean * ersig
                              + dga * ((double)edb[o] - dmean) + (double)edbt[o]);
    pcT[2 * 64 + o] = (float)(dga * w0);
    pcT[3 * 64 + o] = (float)(dga * w1);
    pcT[4 * 64 + o] = (float)(dga * w2);
    pcT[5 * 64 + o] = 0.f;
}

/* dwd transpose */
__global__ __launch_bounds__(256)
void tr_dwd_kernel(const float* __restrict__ dwd, float* __restrict__ outp)
{
    int i = blockIdx.x * 256 + threadIdx.x;
    if (i < Kk * CE * CE) {
        int k = i / (CE * CE), r = i % (CE * CE);
        int o = r >> 6, c = r & 63;
        outp[((long)k * CE + c) * CE + o] = dwd[i];
    }
}

/* wa||wb transpose */
__global__ __launch_bounds__(256)
void tr_wab_kernel(const float* __restrict__ dwa, const float* __restrict__ dwb,
                   float* __restrict__ outp)
{
    int i = blockIdx.x * 256 + threadIdx.x;
    if (i < CE * 96) {
        int c = i / 96, j = i % 96;
        float v = (j < 48) ? dwa[j * CE + c] : dwb[(j - 48) * CE + c];
        outp[i] = v;
    }
}

/* penc helper for datt (ps stride 26, pad col zeroed) */
__device__ __forceinline__ void penc_tile(int tid, int NT, const float* xp,
    const float (*attE_s)[Vn][Vn], const float* ewd_s, const float (*pc_s)[6],
    float (*xs)[Vn], float* ez, float (*ps)[26])
{
    __syncthreads();
    for (int i = tid; i < CIN * Vn; i += NT) { int c = i / Vn, v = i % Vn; xs[c][v] = xp[c * TV + v]; }
    __syncthreads();
    for (int i = tid; i < Kk * CIN * Vn; i += NT) {
        int w = i % Vn, c = (i / Vn) % CIN, k = i / (Vn * CIN);
        float s = 0.f;
        #pragma unroll
        for (int v = 0; v < Vn; ++v) s += xs[c][v] * attE_s[k][v][w];
        ez[i] = s;
    }
    __syncthreads();
    for (int i = tid; i < CE * Vn; i += NT) {
        int w = i % Vn, o = i / Vn;
        float y = 0.f;
        #pragma unroll
        for (int k = 0; k < Kk; ++k)
            #pragma unroll
            for (int c = 0; c < CIN; ++c)
                y += ewd_s[(k * CE + o) * CIN + c] * ez[(k * CIN + c) * Vn + w];
        float val = pc_s[o][0] * y + pc_s[o][1]
                  + pc_s[o][2] * xs[0][w] + pc_s[o][3] * xs[1][w] + pc_s[o][4] * xs[2][w];
        ps[o][w] = fmaxf(val, 0.f);
    }
    for (int i = tid; i < CE; i += NT) ps[i][25] = 0.f;
    __syncthreads();
}

/* DEC ATT v2 — batched: grid 2*N*DSEG; partials to d_out scratch */
__global__ __launch_bounds__(512)
void datt_kernel(const float* __restrict__ x, const float* __restrict__ attEpB,
                 const float* __restrict__ ewd, const float* __restrict__ pcTB,
                 const float* __restrict__ wabTg,
                 const float* __restrict__ dba, const float* __restrict__ dbb,
                 float* __restrict__ attp)
{
    __shared__ float attE_s[Kk][Vn][Vn];
    __shared__ float ewd_s[Kk * CE * CIN];
    __shared__ float pc_s[CE][6];
    __shared__ float bias_s[96];
    __shared__ float xs[CIN][Vn];
    __shared__ float ez[Kk * CIN * Vn];
    __shared__ __align__(16) float ps[CE][26];
    __shared__ __align__(16) float fab[96][26];
    int b = blockIdx.x, s = b % DSEG, n = (b / DSEG) % N_, br = b / (DSEG * N_);
    const float* attEp = attEpB + (long)br * AEP_BR;
    const float* pcT = pcTB + br * 384;
    const float* xb = x + (long)br * (CIN * TV);
    int tid = threadIdx.x;
    for (int i = tid; i < Kk * VV; i += 512) {
        int k = i / 625, r = i - k * 625, v = r / 25, w = r - (r / 25) * 25;
        ((float*)attE_s)[i] = attEp[(long)n * 2100 + (k * 25 + v) * 28 + w];
    }
    for (int i = tid; i < Kk * CE * CIN; i += 512) ewd_s[i] = ewd[i];
    for (int i = tid; i < CE * 6; i += 512) pc_s[i & 63][i >> 6] = pcT[i];
    for (int i = tid; i < 96; i += 512) bias_s[i] = (i < 48) ? dba[i] : dbb[i - 48];

    int sk = tid / 169, sr = tid % 169;
    int sv0 = (sr / 13) * 2, sw0 = (sr % 13) * 2;
    float acc00 = 0.f, acc01 = 0.f, acc10 = 0.f, acc11 = 0.f;
    int fj0 = (tid / 13) * 4, fv0 = (tid % 13) * 2;

    const int TS = Tn / DSEG;
    for (int t = s * TS; t < s * TS + TS; ++t) {
        const float* xp = xb + (long)n * (Mn * CIN * TV) + t * Vn;
        penc_tile(tid, 512, xp, attE_s, ewd_s, pc_s, xs, ez, ps);
        if (tid < 312) {
            float ft[4][2] = {{0.f,0.f},{0.f,0.f},{0.f,0.f},{0.f,0.f}};
            const float* wg = wabTg + fj0;
            #pragma unroll 8
            for (int c = 0; c < 64; ++c) {
                f4 wv = *(const f4*)&wg[c * 96];
                f2 pv = *(const f2*)&ps[c][fv0];
                #pragma unroll
                for (int j = 0; j < 4; ++j) {
                    ft[j][0] += wv[j] * pv[0];
                    ft[j][1] += wv[j] * pv[1];
                }
            }
            #pragma unroll
            for (int j = 0; j < 4; ++j) {
                f2 r = { ft[j][0] + bias_s[fj0 + j], ft[j][1] + bias_s[fj0 + j] };
                *(f2*)&fab[fj0 + j][fv0] = r;
            }
        }
        __syncthreads();
        if (tid < 507) {
            #pragma unroll
            for (int i = 0; i < INTER_; ++i) {
                f2 a = *(const f2*)&fab[sk * INTER_ + i][sv0];
                f2 bb2 = *(const f2*)&fab[48 + sk * INTER_ + i][sw0];
                acc00 += a[0] * bb2[0]; acc01 += a[0] * bb2[1];
                acc10 += a[1] * bb2[0]; acc11 += a[1] * bb2[1];
            }
        }
    }
    if (tid < 507) {
        long ob = (((long)((br * N_ + n) * Kk + sk)) * DSEG + s) * VV;
        attp[ob + sv0 * 25 + sw0] = acc00;
        if (sw0 + 1 < 25)                 attp[ob + sv0 * 25 + sw0 + 1] = acc01;
        if (sv0 + 1 < 25)                 attp[ob + (sv0 + 1) * 25 + sw0] = acc10;
        if (sv0 + 1 < 25 && sw0 + 1 < 25) attp[ob + (sv0 + 1) * 25 + sw0 + 1] = acc11;
    }
}

/* =================================================================
 * DECY0: BN stats of raw dec-y — ONE BRANCH PER BLOCK (unchanged)
 * ================================================================= */
template<int TTC>
__global__ __launch_bounds__(128)
void decy0_kernel(const float* __restrict__ x,
                  const float* __restrict__ attEp,
                  const float* __restrict__ attDp,
                  const float* __restrict__ ewd,
                  const float* __restrict__ pcTg,
                  const float* __restrict__ dwdTg,
                  float* __restrict__ outp)
{
    constexpr int TBc = Tn / TTC;
    __shared__ __align__(16) float psT[25][68];
    __shared__ __align__(16) float dz_s[64][36];
    __shared__ __align__(16) float attD_s[Kk][25][32];
    __shared__ __align__(16) float ewdT_s[9][64];
    __shared__ __align__(16) float ez_s[9][28];
    __shared__ float xs[3][25];

    int b = blockIdx.x;
    int br = b / (N_ * TBc);
    int rem = b - br * (N_ * TBc);
    int n = rem / TBc, tb = rem - (rem / TBc) * TBc;
    int tid = threadIdx.x;
    int tq = tid >> 3, tw8 = tid & 7;
    int q0 = tq * 4, w0 = tw8 * 4;

    for (int i = tid; i < 576; i += 128) {
        int kc = i >> 6, o = i & 63;
        int k = kc / 3, c = kc - k * 3;
        ewdT_s[kc][o] = ewd[(k * 64 + o) * 3 + c];
    }
    for (int i = tid; i < 600; i += 128) {
        int r = i * 4;
        *(f4*)&((float*)attD_s)[r] = *(const f4*)&attDp[(long)br * ADP_BR + n * 2400 + r];
    }

    float s1_[4] = {0.f,0.f,0.f,0.f}, s2_[4] = {0.f,0.f,0.f,0.f};

    for (int tt = 0; tt < TTC; ++tt) {
        int t = tb * TTC + tt;
        __syncthreads();
        for (int i = tid; i < 75; i += 128) {
            int c = i / 25, v = i - (i / 25) * 25;
            xs[c][v] = x[(long)br * (CIN * TV) + (long)n * (Mn * CIN * TV)
                         + c * TV + t * 25 + v];
        }
        __syncthreads();
        if (tid < 72) {
            int kc = tid >> 3, wg = tid & 7;
            if (wg < 7) {
                int k = kc / 3, c = kc - k * 3;
                const float* aE = attEp + (long)br * AEP_BR + n * 2100 + k * 700;
                float e0 = 0.f, e1 = 0.f, e2 = 0.f, e3 = 0.f;
                #pragma unroll
                for (int v = 0; v < 25; ++v) {
                    f4 ae = *(const f4*)&aE[v * 28 + wg * 4];
                    float xv = xs[c][v];
                    e0 += xv * ae[0]; e1 += xv * ae[1];
                    e2 += xv * ae[2]; e3 += xv * ae[3];
                }
                f4 r = { e0, e1, e2, e3 };
                *(f4*)&ez_s[kc][wg * 4] = r;
            }
        }
        __syncthreads();
        for (int g = tid; g < 400; g += 128) {
            int og = (g & 15) << 2, w = g >> 4;
            float y0 = 0.f, y1 = 0.f, y2 = 0.f, y3 = 0.f;
            #pragma unroll
            for (int kc = 0; kc < 9; ++kc) {
                f4 wt = *(const f4*)&ewdT_s[kc][og];
                float ev = ez_s[kc][w];
                y0 += wt[0] * ev; y1 += wt[1] * ev;
                y2 += wt[2] * ev; y3 += wt[3] * ev;
            }
            const float* pcb = pcTg + br * 384;
            f4 al = *(const f4*)&pcb[0 * 64 + og];
            f4 be = *(const f4*)&pcb[1 * 64 + og];
            f4 d0 = *(const f4*)&pcb[2 * 64 + og];
            f4 d1 = *(const f4*)&pcb[3 * 64 + og];
            f4 d2 = *(const f4*)&pcb[4 * 64 + og];
            float x0 = xs[0][w], x1 = xs[1][w], x2 = xs[2][w];
            f4 r;
            r[0] = fmaxf(al[0] * y0 + be[0] + d0[0] * x0 + d1[0] * x1 + d2[0] * x2, 0.f);
            r[1] = fmaxf(al[1] * y1 + be[1] + d0[1] * x0 + d1[1] * x1 + d2[1] * x2, 0.f);
            r[2] = fmaxf(al[2] * y2 + be[2] + d0[2] * x0 + d1[2] * x1 + d2[2] * x2, 0.f);
            r[3] = fmaxf(al[3] * y3 + be[3] + d0[3] * x0 + d1[3] * x1 + d2[3] * x2, 0.f);
            *(f4*)&psT[w][og] = r;
        }
        float acc[4][4];
        #pragma unroll
        for (int j = 0; j < 4; ++j)
            #pragma unroll
            for (int m = 0; m < 4; ++m) acc[j][m] = 0.f;
        for (int k = 0; k < Kk; ++k) {
            __syncthreads();
            {
                float dzt[4][4];
                #pragma unroll
                for (int j = 0; j < 4; ++j)
                    #pragma unroll
                    for (int m = 0; m < 4; ++m) dzt[j][m] = 0.f;
                for (int v = 0; v < 25; ++v) {
                    f4 pa = *(const f4*)&psT[v][q0];
                    f4 ad = *(const f4*)&attD_s[k][v][w0];
                    #pragma unroll
                    for (int j = 0; j < 4; ++j)
                        #pragma unroll
                        for (int m = 0; m < 4; ++m) dzt[j][m] += pa[j] * ad[m];
                }
                #pragma unroll
                for (int j = 0; j < 4; ++j) {
                    f4 wv = { dzt[j][0], dzt[j][1], dzt[j][2], dzt[j][3] };
                    *(f4*)&dz_s[q0 + j][w0] = wv;
                }
            }
            __syncthreads();
            const float* wgp = dwdTg + k * 4096 + q0;
            #pragma unroll 8
            for (int c = 0; c < 64; ++c) {
                f4 wv = *(const f4*)&wgp[c * 64];
                f4 zv = *(const f4*)&dz_s[c][w0];
                #pragma unroll
                for (int j = 0; j < 4; ++j)
                    #pragma unroll
                    for (int m = 0; m < 4; ++m) acc[j][m] += wv[j] * zv[m];
            }
        }
        #pragma unroll
        for (int m = 0; m < 4; ++m) if (w0 + m < 25)
            #pragma unroll
            for (int j = 0; j < 4; ++j) {
                float a = acc[j][m]; s1_[j] += a; s2_[j] += a * a;
            }
    }
    float* red = (float*)dz_s;
    #pragma unroll
    for (int pass = 0; pass < 2; ++pass) {
        __syncthreads();
        #pragma unroll
        for (int j = 0; j < 4; ++j)
            red[(q0 + j) * 8 + tw8] = pass ? s2_[j] : s1_[j];
        __syncthreads();
        if (tid < 64) {
            float a = 0.f;
            #pragma unroll
            for (int q = 0; q < 8; ++q) a += red[tid * 8 + q];
            long pb = (((long)br * N_ + n) * TBc + tb) * 128;
            outp[pb + tid * 2 + pass] = a;
        }
    }
}

/* =================================================================
 * DECY1 v3 (proven best): 128 threads, sequential u, TTC=2,
 * pcT/yc staged in LDS. LDS 51200B -> 3 blocks/CU.
 * ================================================================= */
template<int TTC>
__global__ __launch_bounds__(128)
void decy1_kernel(const float* __restrict__ x,
                  const float* __restrict__ attEp,
                  const float* __restrict__ attDp,
                  const float* __restrict__ ewd,
                  const float* __restrict__ pcTg,
                  const float* __restrict__ ycb,
                  const float* __restrict__ dwdTg,
                  float* __restrict__ outp)
{
    constexpr int TBc = Tn / TTC;
    __shared__ __align__(16) float psT[2][25][68];
    __shared__ __align__(16) float dz_s[64][36];
    __shared__ __align__(16) float attD_s[2][Kk][25][32];
    __shared__ __align__(16) float ewdT_s[9][64];
    __shared__ __align__(16) float ez_s[2][9][28];
    __shared__ __align__(16) float pcT_s[2][6][64];
    __shared__ __align__(16) float yc_s[2][64][2];
    __shared__ float xs[2][3][25];

    int b = blockIdx.x, tb = b % TBc, n = b / TBc;
    int tid = threadIdx.x;
    int tq = tid >> 3;
    int tw8 = tid & 7;
    int q0 = tq * 4, w0 = tw8 * 4;

    for (int i = tid; i < 576; i += 128) {
        int kc = i >> 6, o = i & 63;
        int k = kc / 3, c = kc - k * 3;
        ewdT_s[kc][o] = ewd[(k * 64 + o) * 3 + c];
    }
    for (int i = tid; i < 1200; i += 128) {
        int u2 = i / 600, r = (i - u2 * 600) * 4;
        *(f4*)&((float*)attD_s)[u2 * 2400 + r] =
            *(const f4*)&attDp[(long)u2 * ADP_BR + n * 2400 + r];
    }
    for (int i = tid; i < 768; i += 128) ((float*)pcT_s)[i] = pcTg[i];
    for (int i = tid; i < 256; i += 128) ((float*)yc_s)[i] = ycb[i];

    for (int tt = 0; tt < TTC; ++tt) {
        int t = tb * TTC + tt;
        __syncthreads();   /* staging / prev rr readers done */
        for (int i = tid; i < 150; i += 128) {
            int uu = i / 75, r = i - uu * 75, c = r / 25, v = r - (r / 25) * 25;
            xs[uu][c][v] = x[(((long)n * 2 + uu) * 3 + c) * TV + t * 25 + v];
        }
        __syncthreads();
        for (int g = tid; g < 144; g += 128) {
            int u2 = g >= 72; int gg = g - u2 * 72;
            int kc = gg >> 3, wg = gg & 7;
            if (wg < 7) {
                int k = kc / 3, c = kc - k * 3;
                const float* aE = attEp + u2 * AEP_BR + n * 2100 + k * 700;
                float e0 = 0.f, e1 = 0.f, e2 = 0.f, e3 = 0.f;
                #pragma unroll
                for (int v = 0; v < 25; ++v) {
                    f4 ae = *(const f4*)&aE[v * 28 + wg * 4];
                    float xv = xs[u2][c][v];
                    e0 += xv * ae[0]; e1 += xv * ae[1];
                    e2 += xv * ae[2]; e3 += xv * ae[3];
                }
                f4 r = { e0, e1, e2, e3 };
                *(f4*)&ez_s[u2][kc][wg * 4] = r;
            }
        }
        __syncthreads();
        for (int g = tid; g < 800; g += 128) {
            int u2 = g >= 400; int gg = g - u2 * 400;
            int og = (gg & 15) << 2, w = gg >> 4;
            float y0 = 0.f, y1 = 0.f, y2 = 0.f, y3 = 0.f;
            #pragma unroll
            for (int kc = 0; kc < 9; ++kc) {
                f4 wt = *(const f4*)&ewdT_s[kc][og];
                float ev = ez_s[u2][kc][w];
                y0 += wt[0] * ev; y1 += wt[1] * ev;
                y2 += wt[2] * ev; y3 += wt[3] * ev;
            }
            const float* pcb = &pcT_s[u2][0][0];
            f4 al = *(const f4*)&pcb[0 * 64 + og];
            f4 be = *(const f4*)&pcb[1 * 64 + og];
            f4 d0 = *(const f4*)&pcb[2 * 64 + og];
            f4 d1 = *(const f4*)&pcb[3 * 64 + og];
            f4 d2 = *(const f4*)&pcb[4 * 64 + og];
            float x0 = xs[u2][0][w], x1 = xs[u2][1][w], x2 = xs[u2][2][w];
            f4 r;
            r[0] = fmaxf(al[0] * y0 + be[0] + d0[0] * x0 + d1[0] * x1 + d2[0] * x2, 0.f);
            r[1] = fmaxf(al[1] * y1 + be[1] + d0[1] * x0 + d1[1] * x1 + d2[1] * x2, 0.f);
            r[2] = fmaxf(al[2] * y2 + be[2] + d0[2] * x0 + d1[2] * x1 + d2[2] * x2, 0.f);
            r[3] = fmaxf(al[3] * y3 + be[3] + d0[3] * x0 + d1[3] * x1 + d2[3] * x2, 0.f);
            *(f4*)&psT[u2][w][og] = r;
        }
        for (int u2 = 0; u2 < 2; ++u2) {
            float acc[4][4];
            #pragma unroll
            for (int j = 0; j < 4; ++j)
                #pragma unroll
                for (int m = 0; m < 4; ++m) acc[j][m] = 0.f;
            for (int k = 0; k < Kk; ++k) {
                __syncthreads();
                {
                    float dzt[4][4];
                    #pragma unroll
                    for (int j = 0; j < 4; ++j)
                        #pragma unroll
                        for (int m = 0; m < 4; ++m) dzt[j][m] = 0.f;
                    for (int v = 0; v < 25; ++v) {
                        f4 pa = *(const f4*)&psT[u2][v][q0];
                        f4 ad = *(const f4*)&attD_s[u2][k][v][w0];
                        #pragma unroll
                        for (int j = 0; j < 4; ++j)
                            #pragma unroll
                            for (int m = 0; m < 4; ++m) dzt[j][m] += pa[j] * ad[m];
                    }
                    #pragma unroll
                    for (int j = 0; j < 4; ++j) {
                        f4 wv = { dzt[j][0], dzt[j][1], dzt[j][2], dzt[j][3] };
                        *(f4*)&dz_s[q0 + j][w0] = wv;
                    }
                }
                __syncthreads();
                const float* wgp = dwdTg + k * 4096 + q0;
                #pragma unroll 8
                for (int c = 0; c < 64; ++c) {
                    f4 wv = *(const f4*)&wgp[c * 64];
                    f4 zv = *(const f4*)&dz_s[c][w0];
                    #pragma unroll
                    for (int j = 0; j < 4; ++j)
                        #pragma unroll
                        for (int m = 0; m < 4; ++m) acc[j][m] += wv[j] * zv[m];
                }
            }
            const float* ycu = &yc_s[u2][0][0];
            #pragma unroll
            for (int m = 0; m < 4; ++m) {
                int w = w0 + m;
                if (w < 25) {
                    #pragma unroll
                    for (int j = 0; j < 4; ++j) {
                        float pd = ycu[(q0 + j) * 2] * acc[j][m]
                                 + ycu[(q0 + j) * 2 + 1] + psT[u2][w][q0 + j];
                        psT[u2][w][q0 + j] = fmaxf(pd, 0.f);
                    }
                }
            }
        }
        __syncthreads();
        for (int i = tid; i < 169; i += 128) {
            int tv = i / 13, tw2 = i % 13;
            int v0 = tv * 2, ww0 = tw2 * 2;
            float r00 = 0.f, r01 = 0.f, r10 = 0.f, r11 = 0.f;
            for (int c = 0; c < 64; c += 4) {
                f4 a0 = *(const f4*)&psT[0][v0][c];
                f4 a1 = *(const f4*)&psT[0][v0 + 1][c];
                f4 b0 = *(const f4*)&psT[1][ww0][c];
                f4 b1 = *(const f4*)&psT[1][ww0 + 1][c];
                #pragma unroll
                for (int q = 0; q < 4; ++q) {
                    r00 += a0[q] * b0[q]; r01 += a0[q] * b1[q];
                    r10 += a1[q] * b0[q]; r11 += a1[q] * b1[q];
                }
            }
            long ob = ((long)n * Tn + t) * VV;
            outp[ob + v0 * 25 + ww0] = r00;
            if (ww0 + 1 < 25)                outp[ob + v0 * 25 + ww0 + 1] = r01;
            if (v0 + 1 < 25)                 outp[ob + (v0 + 1) * 25 + ww0] = r10;
            if (v0 + 1 < 25 && ww0 + 1 < 25) outp[ob + (v0 + 1) * 25 + ww0 + 1] = r11;
        }
    }
}

/* DEC finalize — batched: 2 blocks (one per branch) */
__global__ __launch_bounds__(64)
void dec_fin_kernel(const float* __restrict__ partB, int nparts,
                    const float* __restrict__ dg, const float* __restrict__ dbt,
                    float* __restrict__ ycB)
{
    int br = blockIdx.x;
    const float* part = partB + (long)br * nparts * 128;
    float* yc = ycB + br * 128;
    int o = threadIdx.x;
    double s1 = 0, s2 = 0;
    for (int b = 0; b < nparts; ++b) { s1 += part[(long)b * 128 + o * 2]; s2 += part[(long)b * 128 + o * 2 + 1]; }
    double cnt = (double)N_ * Tn * Vn;
    double mean = s1 / cnt, var = s2 / cnt - mean * mean;
    double rsig = 1.0 / sqrt(var + 1e-5);
    double a = (double)dg[o] * rsig;
    yc[o * 2 + 0] = (float)a;
    yc[o * 2 + 1] = (float)((double)dbt[o] - a * mean);
}

/* BN stats over (n,v,w) per t */
__global__ __launch_bounds__(256)
void rrbn_kernel(const float* __restrict__ rr, float* __restrict__ tstats)
{
    int t = blockIdx.x;
    double s = 0.0, s2 = 0.0;
    for (int idx = threadIdx.x; idx < N_ * VV; idx += 256) {
        int n = idx / VV, j = idx % VV;
        float v = rr[((long)n * Tn + t) * VV + j];
        s += v; s2 += (double)v * v;
    }
    __shared__ double rs[256], rs2[256];
    int tid = threadIdx.x;
    rs[tid] = s; rs2[tid] = s2;
    __syncthreads();
    for (int off = 128; off > 0; off >>= 1) {
        if (tid < off) { rs[tid] += rs[tid + off]; rs2[tid] += rs2[tid + off]; }
        __syncthreads();
    }
    if (tid == 0) {
        double cnt = (double)N_ * VV;
        double mean = rs[0] / cnt;
        double var = rs2[0] / cnt - mean * mean;
        tstats[t * 2 + 0] = (float)mean;
        tstats[t * 2 + 1] = (float)(1.0 / sqrt(var + 1e-5));
    }
}

/* FINAL */
__global__ __launch_bounds__(128)
void final_kernel(const float* __restrict__ tstats,
                  const float* __restrict__ x, const float* __restrict__ iparam,
                  const float* __restrict__ tgamma, const float* __restrict__ tbeta,
                  float* out)
{
    int b = blockIdx.x;
    int t = b % Tn, n = b / Tn;
    __shared__ float xa_s[CIN][Vn], xb_s[CIN][Vn];
    __shared__ float ram_s[VV];
    __shared__ float da_s[Vn], db_s[Vn];
    __shared__ float varc[CIN];
    __shared__ float abf;
    int tid = threadIdx.x;

    for (int idx = tid; idx < 2 * CIN * Vn; idx += 128) {
        int half = idx / (CIN * Vn);
        int r = idx % (CIN * Vn);
        int c = r / Vn, v = r % Vn;
        float val = x[(((long)n * Mn + half) * CIN + c) * TV + t * Vn + v];
        if (half == 0) xa_s[c][v] = val; else xb_s[c][v] = val;
    }
    __syncthreads();
    if (tid < CIN) {
        float s = 0.f, s2 = 0.f;
        #pragma unroll
        for (int v = 0; v < Vn; ++v) { float q = xb_s[tid][v]; s += q; s2 += q * q; }
        float mean = s / Vn;
        varc[tid] = (s2 - Vn * mean * mean) / (Vn - 1);
    }
    __syncthreads();
    if (tid == 0) {
        float absum = varc[0] + varc[1] + varc[2];
        abf = (absum < 1e-4f) ? 0.f : 1.f;
    }
    float pct = 0.5f * (tanhf(iparam[0]) + 1.f);
    float mt = tstats[t * 2], rt = tstats[t * 2 + 1];
    float gt = tgamma[t], bt = tbeta[t];
    __syncthreads();

    for (int idx = tid; idx < VV; idx += 128) {
        int v = idx / Vn, w = idx % Vn;
        float rrv = out[(long)b * VV + idx];
        float rbn = gt * (rrv - mt) * rt + bt;
        float ramr = 0.5f * (tanhf(rbn) + 1.f);
        float gsum = 0.f;
        #pragma unroll
        for (int c = 0; c < CIN; ++c) {
            float d = expf(xa_s[c][v]) * expf(-xb_s[c][w]);
            float l = logf(d + 1e-5f);
            gsum += l * l;
        }
        float ramg = expf(-(1.f / 3.f) * gsum);
        float ram = pct * ramr + (1.f - pct) * ramg;
        ram *= abf;
        if (ram < 0.5f) ram = 0.f;
        ram_s[idx] = ram;
    }
    __syncthreads();
    if (tid < Vn) {
        float s = 0.f;
        #pragma unroll
        for (int v = 0; v < Vn; ++v) s += ram_s[v * Vn + tid];
        da_s[tid] = s;
    } else if (tid >= 64 && tid < 64 + Vn) {
        int v = tid - 64;
        float s = 0.f;
        #pragma unroll
        for (int w = 0; w < Vn; ++w) s += ram_s[v * Vn + w];
        db_s[v] = s;
    }
    __syncthreads();
    for (int idx = tid; idx < VV; idx += 128) {
        int v = idx / Vn, w = idx % Vn;
        float ram = ram_s[idx];
        out[(long)b * VV + idx] = ram * rsqrtf(db_s[v] * da_s[w] + 1e-5f);
    }
}

/* ================================================================= */
extern "C" void kernel_launch(void* const* d_in, const int* in_sizes, int n_in,
                              void* d_out, int out_size, void* d_ws, size_t ws_size,
                              hipStream_t stream)
{
    const float* x    = (const float*)d_in[0];
    const float* A    = (const float*)d_in[1];
    const float* ip   = (const float*)d_in[2];
    const float* rg   = (const float*)d_in[3];
    const float* rbta = (const float*)d_in[4];
    const float* ePA  = (const float*)d_in[5];
    const float* ewa  = (const float*)d_in[6];
    const float* eba  = (const float*)d_in[7];
    const float* ewb  = (const float*)d_in[8];
    const float* ebb  = (const float*)d_in[9];
    const float* ewd  = (const float*)d_in[10];
    const float* ebd  = (const float*)d_in[11];  (void)ebd;
    const float* eg   = (const float*)d_in[12];
    const float* ebt  = (const float*)d_in[13];
    const float* edw  = (const float*)d_in[14];
    const float* edb  = (const float*)d_in[15];
    const float* edg  = (const float*)d_in[16];
    const float* edbt = (const float*)d_in[17];
    const float* dPA  = (const float*)d_in[18];
    const float* dwa  = (const float*)d_in[19];
    const float* dba  = (const float*)d_in[20];
    const float* dwb  = (const float*)d_in[21];
    const float* dbb  = (const float*)d_in[22];
    const float* dwd  = (const float*)d_in[23];
    const float* dbd  = (const float*)d_in[24];  (void)dbd;
    const float* dg   = (const float*)d_in[25];
    const float* dbt  = (const float*)d_in[26];

    if (ws_size < (size_t)WS_REQ * sizeof(float)) return;

    float* ws    = (float*)d_ws;
    float* attp  = ws + OFF_ATTP;
    float* part  = ws + OFF_PART;
    float* attEp = ws + OFF_ATTEP;
    float* attDp = ws + OFF_ATTDP;
    double* covp = (double*)(ws + OFF_COV);
    float* pcT   = ws + OFF_PCT;
    float* yc    = ws + OFF_YC;
    float* tst   = ws + OFF_TST;
    float* dwdTg = ws + OFF_DWDT;
    float* wabTg = ws + OFF_WABT;
    float* outf  = (float*)d_out;

    tr_dwd_kernel<<<(Kk * CE * CE + 255) / 256, 256, 0, stream>>>(dwd, dwdTg);
    tr_wab_kernel<<<(CE * 96 + 255) / 256, 256, 0, stream>>>(dwa, dwb, wabTg);

    /* -------- both branches batched per dispatch -------- */
    att_kernel<<<2 * N_ * Kk * ESEG, 640, 0, stream>>>(
        x, ewa, eba, ewb, ebb, attp);
    softmax_kernel<ESEG, 28><<<2 * N_ * Kk, 256, 0, stream>>>(attp, A, ePA, attEp);
    xcov_kernel<<<240, 256, 0, stream>>>(x, covp);
    ey_stat_kernel<<<2 * N_ * EYB, 256, 0, stream>>>(x, attEp, ewd, part);
    enc_fin_kernel<<<2, 64, 0, stream>>>(part, covp, eg, ebt, edw, edb, edg, edbt, pcT);
    /* datt partials use d_out as scratch (dead until decy1 overwrites) */
    datt_kernel<<<2 * N_ * DSEG, 512, 0, stream>>>(
        x, attEp, ewd, pcT, wabTg, dba, dbb, outf);
    softmax_kernel<DSEG, 32><<<2 * N_ * Kk, 256, 0, stream>>>(outf, A, dPA, attDp);

    /* dec-y stats: one branch per block, TTC=5 -> 7680 blocks */
    decy0_kernel<5><<<2 * N_ * (Tn / 5), 128, 0, stream>>>(
        x, attEp, attDp, ewd, pcT, dwdTg, part);
    dec_fin_kernel<<<2, 64, 0, stream>>>(part, N_ * (Tn / 5), dg, dbt, yc);
    /* full dec out + rr: proven best (128 thr, seq-u, TTC=2) */
    decy1_kernel<2><<<N_ * (Tn / 2), 128, 0, stream>>>(
        x, attEp, attDp, ewd, pcT, yc, dwdTg, outf);

    rrbn_kernel<<<Tn, 256, 0, stream>>>(outf, tst);
    final_kernel<<<N_ * Tn, 128, 0, stream>>>(tst, x, ip, rg, rbta, outf);
}

// Round 19
// 3781.404 us; speedup vs baseline: 1.1703x; 1.0120x over previous
//
#include <hip/hip_runtime.h>
#include <math.h>

#define N_     64
#define Mn     2
#define Tn     300
#define Vn     25
#define Kk     3
#define CIN    3
#define CE     64
#define INTER_ 16
#define TV     7500
#define VV     625
#define ESEG   10     /* enc att t-segments (30 t each); partials in d_out */
#define DSEG   30     /* dec att t-segments (10 t each); partials in d_out */
#define EYB    12     /* ey_stat t-blocks (25 t each) */

typedef float f4 __attribute__((ext_vector_type(4)));
typedef float f2 __attribute__((ext_vector_type(2)));

/* ---------------- workspace layout (float offsets) ----------------
 * region0: ey part (197K) then decy0 partials 2*N*60*128 = 983,040.
 * att partials (2*N*K*ESEG*VV = 2.4M) and datt partials (7.2M) live
 * in d_out (dead until overwritten; consumed by the softmax right
 * after each producer). */
#define OFF_PART  0L
#define OFF_ATTEP 1200000L   /* [2] 268,800 */
#define OFF_ATTDP 1468800L   /* [2] 307,200 */
#define OFF_COV   1776000L   /* doubles: 2*120*9 -> 4320 floats */
#define OFF_PCT   1780320L   /* [2][6][64] = 768 */
#define OFF_YC    1781088L   /* 256 */
#define OFF_TST   1781344L   /* 600 */
#define OFF_DWDT  1781944L   /* 12288 */
#define OFF_WABT  1794232L   /* 6144 */
#define WS_REQ    1800376L

#define AEP_BR 134400   /* attEp branch stride (floats) */
#define ADP_BR 153600   /* attDp branch stride */

/* =================================================================
 * ENC ATT partials — batched over branches
 * ================================================================= */
__global__ __launch_bounds__(640)
void att_kernel(const float* __restrict__ x,
                const float* __restrict__ wa, const float* __restrict__ ba,
                const float* __restrict__ wb, const float* __restrict__ bb,
                float* __restrict__ att_partial)
{
    int b = blockIdx.x;
    int s = b % ESEG;
    int k = (b / ESEG) % Kk;
    int n = (b / (ESEG * Kk)) % N_;
    int br = b / (ESEG * Kk * N_);
    const float* xp = x + (long)br * (CIN * TV) + (long)n * (Mn * CIN * TV);

    __shared__ float xs[CIN][Vn];
    __shared__ float fa_s[INTER_][Vn];
    __shared__ float fb_s[INTER_][Vn];

    int tid = threadIdx.x;
    float acc = 0.f;
    const int TSEG = Tn / ESEG;
    int t0 = s * TSEG;
    for (int t = t0; t < t0 + TSEG; ++t) {
        __syncthreads();
        for (int idx = tid; idx < CIN * Vn; idx += 640) {
            int c = idx / Vn, v = idx % Vn;
            xs[c][v] = xp[(long)c * TV + t * Vn + v];
        }
        __syncthreads();
        for (int idx = tid; idx < 2 * INTER_ * Vn; idx += 640) {
            int j = idx;
            const float* w; const float* bias; float (*dst)[Vn];
            if (j < INTER_ * Vn) { w = wa; bias = ba; dst = fa_s; }
            else { j -= INTER_ * Vn; w = wb; bias = bb; dst = fb_s; }
            int i = j / Vn, v = j % Vn;
            float sum = bias[k * INTER_ + i];
            const float* wr = w + (k * INTER_ + i) * CIN;
            #pragma unroll
            for (int c = 0; c < CIN; ++c) sum += wr[c] * xs[c][v];
            dst[i][v] = sum;
        }
        __syncthreads();
        if (tid < VV) {
            int v = tid / Vn, w = tid % Vn;
            float a = 0.f;
            #pragma unroll
            for (int i = 0; i < INTER_; ++i) a += fa_s[i][v] * fb_s[i][w];
            acc += a;
        }
    }
    if (tid < VV)
        att_partial[(((long)((br * N_ + n) * Kk + k)) * ESEG + s) * VV + tid] = acc;
}

/* softmax over v per (br,n,k,w), then + (A+PA); writes PADDED layout. */
template<int SEGS, int PADW>
__global__ __launch_bounds__(256)
void softmax_kernel(const float* __restrict__ att_partial,
                    const float* __restrict__ A, const float* __restrict__ PA,
                    float* __restrict__ attP)
{
    int b = blockIdx.x;
    int k = b % Kk;
    __shared__ float as[VV];
    int tid = threadIdx.x;
    for (int idx = tid; idx < VV; idx += 256) {
        float s = 0.f;
        for (int seg = 0; seg < SEGS; ++seg)
            s += att_partial[((long)b * SEGS + seg) * VV + idx];
        as[idx] = s * (1.0f / (INTER_ * Tn));
    }
    __syncthreads();
    if (tid < Vn) {
        int w = tid;
        float m = -1e30f;
        #pragma unroll
        for (int v = 0; v < Vn; ++v) m = fmaxf(m, as[v * Vn + w]);
        float e[Vn];
        float den = 0.f;
        #pragma unroll
        for (int v = 0; v < Vn; ++v) { e[v] = expf(as[v * Vn + w] - m); den += e[v]; }
        float inv = 1.f / den;
        #pragma unroll
        for (int v = 0; v < Vn; ++v)
            attP[((long)b * Vn + v) * PADW + w] =
                e[v] * inv + A[k * VV + v * Vn + w] + PA[k * VV + v * Vn + w];
    } else if (tid < PADW) {
        #pragma unroll
        for (int v = 0; v < Vn; ++v)
            attP[((long)b * Vn + v) * PADW + tid] = 0.f;
    }
}

/* x covariance partials — batched: grid 240, 120 per branch */
__global__ __launch_bounds__(256)
void xcov_kernel(const float* __restrict__ x, double* __restrict__ part)
{
    int br = blockIdx.x / 120, g = blockIdx.x % 120;
    const float* xbase = x + (long)br * (CIN * TV);
    double a[9];
    #pragma unroll
    for (int q = 0; q < 9; ++q) a[q] = 0.0;
    for (long idx = (long)g * 256 + threadIdx.x; idx < (long)N_ * TV;
         idx += 120L * 256) {
        int n = (int)(idx / TV);
        int j = (int)(idx % TV);
        const float* xp = xbase + (long)n * (Mn * CIN * TV) + j;
        float x0 = xp[0], x1 = xp[TV], x2 = xp[2 * TV];
        a[0] += x0; a[1] += x1; a[2] += x2;
        a[3] += (double)x0 * x0; a[4] += (double)x0 * x1; a[5] += (double)x0 * x2;
        a[6] += (double)x1 * x1; a[7] += (double)x1 * x2; a[8] += (double)x2 * x2;
    }
    __shared__ double red[256];
    int tid = threadIdx.x;
    for (int q = 0; q < 9; ++q) {
        red[tid] = a[q];
        __syncthreads();
        for (int off = 128; off > 0; off >>= 1) {
            if (tid < off) red[tid] += red[tid + off];
            __syncthreads();
        }
        if (tid == 0) part[(long)blockIdx.x * 9 + q] = red[0];
        __syncthreads();
    }
}

/* ENC y stats — batched: grid 2*N*EYB */
__global__ __launch_bounds__(256)
void ey_stat_kernel(const float* __restrict__ x, const float* __restrict__ attEpB,
                    const float* __restrict__ ewd, float* __restrict__ part)
{
    __shared__ float attE_s[Kk][Vn][Vn];
    __shared__ float ewd_s[Kk * CE * CIN];
    __shared__ float xs[CIN][Vn];
    __shared__ float ez[Kk * CIN * Vn];
    __shared__ float ys[CE][Vn];
    int b = blockIdx.x, tb = b % EYB, n = (b / EYB) % N_, br = b / (EYB * N_);
    const float* attEp = attEpB + (long)br * AEP_BR;
    const float* xb = x + (long)br * (CIN * TV);
    int tid = threadIdx.x;
    for (int i = tid; i < Kk * VV; i += 256) {
        int k = i / 625, r = i - k * 625, v = r / 25, w = r - (r / 25) * 25;
        ((float*)attE_s)[i] = attEp[(long)n * 2100 + (k * 25 + v) * 28 + w];
    }
    for (int i = tid; i < Kk * CE * CIN; i += 256) ewd_s[i] = ewd[i];
    float s1 = 0.f, s2 = 0.f;
    for (int t = tb * 25; t < tb * 25 + 25; ++t) {
        const float* xp = xb + (long)n * (Mn * CIN * TV) + t * Vn;
        __syncthreads();
        for (int i = tid; i < CIN * Vn; i += 256) { int c = i / Vn, v = i % Vn; xs[c][v] = xp[c * TV + v]; }
        __syncthreads();
        for (int i = tid; i < Kk * CIN * Vn; i += 256) {
            int w = i % Vn, c = (i / Vn) % CIN, k = i / (Vn * CIN);
            float s = 0.f;
            #pragma unroll
            for (int v = 0; v < Vn; ++v) s += xs[c][v] * attE_s[k][v][w];
            ez[i] = s;
        }
        __syncthreads();
        for (int i = tid; i < CE * Vn; i += 256) {
            int w = i % Vn, o = i / Vn;
            float y = 0.f;
            #pragma unroll
            for (int k = 0; k < Kk; ++k)
                #pragma unroll
                for (int c = 0; c < CIN; ++c)
                    y += ewd_s[(k * CE + o) * CIN + c] * ez[(k * CIN + c) * Vn + w];
            ys[o][w] = y;
        }
        __syncthreads();
        if (tid < CE) {
            #pragma unroll
            for (int w = 0; w < Vn; ++w) { float y = ys[tid][w]; s1 += y; s2 += y * y; }
        }
    }
    if (tid < CE) { part[(long)b * 128 + tid * 2] = s1; part[(long)b * 128 + tid * 2 + 1] = s2; }
}

/* ENC finalize — batched: 2 blocks (one per branch) */
__global__ __launch_bounds__(64)
void enc_fin_kernel(const float* __restrict__ partB,
                    const double* __restrict__ covpB,
                    const float* __restrict__ eg, const float* __restrict__ ebt,
                    const float* __restrict__ edw, const float* __restrict__ edb,
                    const float* __restrict__ edg, const float* __restrict__ edbt,
                    float* __restrict__ pcTB)
{
    int br = blockIdx.x;
    const float* part = partB + (long)br * (N_ * EYB * 128);
    const double* covp = covpB + (long)br * (120 * 9);
    float* pcT = pcTB + br * 384;
    int o = threadIdx.x;
    __shared__ double tot[9];
    if (o < 9) { double s = 0; for (int g = 0; g < 120; ++g) s += covp[(long)g * 9 + o]; tot[o] = s; }
    double s1 = 0, s2 = 0;
    for (int b = 0; b < N_ * EYB; ++b) { s1 += part[(long)b * 128 + o * 2]; s2 += part[(long)b * 128 + o * 2 + 1]; }
    __syncthreads();
    double cnt = (double)N_ * Tn * Vn;
    double mean = s1 / cnt, var = s2 / cnt - mean * mean;
    double ersig = 1.0 / sqrt(var + 1e-5);
    double alpha = (double)eg[o] * ersig;
    double inv = 1.0 / cnt;
    double mu0 = tot[0] * inv, mu1 = tot[1] * inv, mu2 = tot[2] * inv;
    double c00 = tot[3] * inv - mu0 * mu0, c01 = tot[4] * inv - mu0 * mu1, c02 = tot[5] * inv - mu0 * mu2;
    double c11 = tot[6] * inv - mu1 * mu1, c12 = tot[7] * inv - mu1 * mu2, c22 = tot[8] * inv - mu2 * mu2;
    double w0 = edw[o * CIN + 0], w1 = edw[o * CIN + 1], w2 = edw[o * CIN + 2];
    double dmean = w0 * mu0 + w1 * mu1 + w2 * mu2 + (double)edb[o];
    double dvar = w0 * w0 * c00 + w1 * w1 * c11 + w2 * w2 * c22
                + 2.0 * (w0 * w1 * c01 + w0 * w2 * c02 + w1 * w2 * c12);
    double drsig = 1.0 / sqrt(dvar + 1e-5);
    double dga = (double)edg[o] * drsig;
    pcT[0 * 64 + o] = (float)alpha;
    pcT[1 * 64 + o] = (float)((double)ebt[o] - (double)eg[o] * mean * ersig
                              + dga * ((double)edb[o] - dmean) + (double)edbt[o]);
    pcT[2 * 64 + o] = (float)(dga * w0);
    pcT[3 * 64 + o] = (float)(dga * w1);
    pcT[4 * 64 + o] = (float)(dga * w2);
    pcT[5 * 64 + o] = 0.f;
}

/* dwd transpose */
__global__ __launch_bounds__(256)
void tr_dwd_kernel(const float* __restrict__ dwd, float* __restrict__ outp)
{
    int i = blockIdx.x * 256 + threadIdx.x;
    if (i < Kk * CE * CE) {
        int k = i / (CE * CE), r = i % (CE * CE);
        int o = r >> 6, c = r & 63;
        outp[((long)k * CE + c) * CE + o] = dwd[i];
    }
}

/* wa||wb transpose */
__global__ __launch_bounds__(256)
void tr_wab_kernel(const float* __restrict__ dwa, const float* __restrict__ dwb,
                   float* __restrict__ outp)
{
    int i = blockIdx.x * 256 + threadIdx.x;
    if (i < CE * 96) {
        int c = i / 96, j = i % 96;
        float v = (j < 48) ? dwa[j * CE + c] : dwb[(j - 48) * CE + c];
        outp[i] = v;
    }
}

/* penc helper for datt (ps stride 26, pad col zeroed) */
__device__ __forceinline__ void penc_tile(int tid, int NT, const float* xp,
    const float (*attE_s)[Vn][Vn], const float* ewd_s, const float (*pc_s)[6],
    float (*xs)[Vn], float* ez, float (*ps)[26])
{
    __syncthreads();
    for (int i = tid; i < CIN * Vn; i += NT) { int c = i / Vn, v = i % Vn; xs[c][v] = xp[c * TV + v]; }
    __syncthreads();
    for (int i = tid; i < Kk * CIN * Vn; i += NT) {
        int w = i % Vn, c = (i / Vn) % CIN, k = i / (Vn * CIN);
        float s = 0.f;
        #pragma unroll
        for (int v = 0; v < Vn; ++v) s += xs[c][v] * attE_s[k][v][w];
        ez[i] = s;
    }
    __syncthreads();
    for (int i = tid; i < CE * Vn; i += NT) {
        int w = i % Vn, o = i / Vn;
        float y = 0.f;
        #pragma unroll
        for (int k = 0; k < Kk; ++k)
            #pragma unroll
            for (int c = 0; c < CIN; ++c)
                y += ewd_s[(k * CE + o) * CIN + c] * ez[(k * CIN + c) * Vn + w];
        float val = pc_s[o][0] * y + pc_s[o][1]
                  + pc_s[o][2] * xs[0][w] + pc_s[o][3] * xs[1][w] + pc_s[o][4] * xs[2][w];
        ps[o][w] = fmaxf(val, 0.f);
    }
    for (int i = tid; i < CE; i += NT) ps[i][25] = 0.f;
    __syncthreads();
}

/* DEC ATT v2 — batched: grid 2*N*DSEG; partials to d_out scratch */
__global__ __launch_bounds__(512)
void datt_kernel(const float* __restrict__ x, const float* __restrict__ attEpB,
                 const float* __restrict__ ewd, const float* __restrict__ pcTB,
                 const float* __restrict__ wabTg,
                 const float* __restrict__ dba, const float* __restrict__ dbb,
                 float* __restrict__ attp)
{
    __shared__ float attE_s[Kk][Vn][Vn];
    __shared__ float ewd_s[Kk * CE * CIN];
    __shared__ float pc_s[CE][6];
    __shared__ float bias_s[96];
    __shared__ float xs[CIN][Vn];
    __shared__ float ez[Kk * CIN * Vn];
    __shared__ __align__(16) float ps[CE][26];
    __shared__ __align__(16) float fab[96][26];
    int b = blockIdx.x, s = b % DSEG, n = (b / DSEG) % N_, br = b / (DSEG * N_);
    const float* attEp = attEpB + (long)br * AEP_BR;
    const float* pcT = pcTB + br * 384;
    const float* xb = x + (long)br * (CIN * TV);
    int tid = threadIdx.x;
    for (int i = tid; i < Kk * VV; i += 512) {
        int k = i / 625, r = i - k * 625, v = r / 25, w = r - (r / 25) * 25;
        ((float*)attE_s)[i] = attEp[(long)n * 2100 + (k * 25 + v) * 28 + w];
    }
    for (int i = tid; i < Kk * CE * CIN; i += 512) ewd_s[i] = ewd[i];
    for (int i = tid; i < CE * 6; i += 512) pc_s[i & 63][i >> 6] = pcT[i];
    for (int i = tid; i < 96; i += 512) bias_s[i] = (i < 48) ? dba[i] : dbb[i - 48];

    int sk = tid / 169, sr = tid % 169;
    int sv0 = (sr / 13) * 2, sw0 = (sr % 13) * 2;
    float acc00 = 0.f, acc01 = 0.f, acc10 = 0.f, acc11 = 0.f;
    int fj0 = (tid / 13) * 4, fv0 = (tid % 13) * 2;

    const int TS = Tn / DSEG;
    for (int t = s * TS; t < s * TS + TS; ++t) {
        const float* xp = xb + (long)n * (Mn * CIN * TV) + t * Vn;
        penc_tile(tid, 512, xp, attE_s, ewd_s, pc_s, xs, ez, ps);
        if (tid < 312) {
            float ft[4][2] = {{0.f,0.f},{0.f,0.f},{0.f,0.f},{0.f,0.f}};
            const float* wg = wabTg + fj0;
            #pragma unroll 8
            for (int c = 0; c < 64; ++c) {
                f4 wv = *(const f4*)&wg[c * 96];
                f2 pv = *(const f2*)&ps[c][fv0];
                #pragma unroll
                for (int j = 0; j < 4; ++j) {
                    ft[j][0] += wv[j] * pv[0];
                    ft[j][1] += wv[j] * pv[1];
                }
            }
            #pragma unroll
            for (int j = 0; j < 4; ++j) {
                f2 r = { ft[j][0] + bias_s[fj0 + j], ft[j][1] + bias_s[fj0 + j] };
                *(f2*)&fab[fj0 + j][fv0] = r;
            }
        }
        __syncthreads();
        if (tid < 507) {
            #pragma unroll
            for (int i = 0; i < INTER_; ++i) {
                f2 a = *(const f2*)&fab[sk * INTER_ + i][sv0];
                f2 bb2 = *(const f2*)&fab[48 + sk * INTER_ + i][sw0];
                acc00 += a[0] * bb2[0]; acc01 += a[0] * bb2[1];
                acc10 += a[1] * bb2[0]; acc11 += a[1] * bb2[1];
            }
        }
    }
    if (tid < 507) {
        long ob = (((long)((br * N_ + n) * Kk + sk)) * DSEG + s) * VV;
        attp[ob + sv0 * 25 + sw0] = acc00;
        if (sw0 + 1 < 25)                 attp[ob + sv0 * 25 + sw0 + 1] = acc01;
        if (sv0 + 1 < 25)                 attp[ob + (sv0 + 1) * 25 + sw0] = acc10;
        if (sv0 + 1 < 25 && sw0 + 1 < 25) attp[ob + (sv0 + 1) * 25 + sw0 + 1] = acc11;
    }
}

/* =================================================================
 * DECY0: BN stats of raw dec-y — ONE BRANCH PER BLOCK (unchanged)
 * ================================================================= */
template<int TTC>
__global__ __launch_bounds__(128)
void decy0_kernel(const float* __restrict__ x,
                  const float* __restrict__ attEp,
                  const float* __restrict__ attDp,
                  const float* __restrict__ ewd,
                  const float* __restrict__ pcTg,
                  const float* __restrict__ dwdTg,
                  float* __restrict__ outp)
{
    constexpr int TBc = Tn / TTC;
    __shared__ __align__(16) float psT[25][68];
    __shared__ __align__(16) float dz_s[64][36];
    __shared__ __align__(16) float attD_s[Kk][25][32];
    __shared__ __align__(16) float ewdT_s[9][64];
    __shared__ __align__(16) float ez_s[9][28];
    __shared__ float xs[3][25];

    int b = blockIdx.x;
    int br = b / (N_ * TBc);
    int rem = b - br * (N_ * TBc);
    int n = rem / TBc, tb = rem - (rem / TBc) * TBc;
    int tid = threadIdx.x;
    int tq = tid >> 3, tw8 = tid & 7;
    int q0 = tq * 4, w0 = tw8 * 4;

    for (int i = tid; i < 576; i += 128) {
        int kc = i >> 6, o = i & 63;
        int k = kc / 3, c = kc - k * 3;
        ewdT_s[kc][o] = ewd[(k * 64 + o) * 3 + c];
    }
    for (int i = tid; i < 600; i += 128) {
        int r = i * 4;
        *(f4*)&((float*)attD_s)[r] = *(const f4*)&attDp[(long)br * ADP_BR + n * 2400 + r];
    }

    float s1_[4] = {0.f,0.f,0.f,0.f}, s2_[4] = {0.f,0.f,0.f,0.f};

    for (int tt = 0; tt < TTC; ++tt) {
        int t = tb * TTC + tt;
        __syncthreads();
        for (int i = tid; i < 75; i += 128) {
            int c = i / 25, v = i - (i / 25) * 25;
            xs[c][v] = x[(long)br * (CIN * TV) + (long)n * (Mn * CIN * TV)
                         + c * TV + t * 25 + v];
        }
        __syncthreads();
        if (tid < 72) {
            int kc = tid >> 3, wg = tid & 7;
            if (wg < 7) {
                int k = kc / 3, c = kc - k * 3;
                const float* aE = attEp + (long)br * AEP_BR + n * 2100 + k * 700;
                float e0 = 0.f, e1 = 0.f, e2 = 0.f, e3 = 0.f;
                #pragma unroll
                for (int v = 0; v < 25; ++v) {
                    f4 ae = *(const f4*)&aE[v * 28 + wg * 4];
                    float xv = xs[c][v];
                    e0 += xv * ae[0]; e1 += xv * ae[1];
                    e2 += xv * ae[2]; e3 += xv * ae[3];
                }
                f4 r = { e0, e1, e2, e3 };
                *(f4*)&ez_s[kc][wg * 4] = r;
            }
        }
        __syncthreads();
        for (int g = tid; g < 400; g += 128) {
            int og = (g & 15) << 2, w = g >> 4;
            float y0 = 0.f, y1 = 0.f, y2 = 0.f, y3 = 0.f;
            #pragma unroll
            for (int kc = 0; kc < 9; ++kc) {
                f4 wt = *(const f4*)&ewdT_s[kc][og];
                float ev = ez_s[kc][w];
                y0 += wt[0] * ev; y1 += wt[1] * ev;
                y2 += wt[2] * ev; y3 += wt[3] * ev;
            }
            const float* pcb = pcTg + br * 384;
            f4 al = *(const f4*)&pcb[0 * 64 + og];
            f4 be = *(const f4*)&pcb[1 * 64 + og];
            f4 d0 = *(const f4*)&pcb[2 * 64 + og];
            f4 d1 = *(const f4*)&pcb[3 * 64 + og];
            f4 d2 = *(const f4*)&pcb[4 * 64 + og];
            float x0 = xs[0][w], x1 = xs[1][w], x2 = xs[2][w];
            f4 r;
            r[0] = fmaxf(al[0] * y0 + be[0] + d0[0] * x0 + d1[0] * x1 + d2[0] * x2, 0.f);
            r[1] = fmaxf(al[1] * y1 + be[1] + d0[1] * x0 + d1[1] * x1 + d2[1] * x2, 0.f);
            r[2] = fmaxf(al[2] * y2 + be[2] + d0[2] * x0 + d1[2] * x1 + d2[2] * x2, 0.f);
            r[3] = fmaxf(al[3] * y3 + be[3] + d0[3] * x0 + d1[3] * x1 + d2[3] * x2, 0.f);
            *(f4*)&psT[w][og] = r;
        }
        float acc[4][4];
        #pragma unroll
        for (int j = 0; j < 4; ++j)
            #pragma unroll
            for (int m = 0; m < 4; ++m) acc[j][m] = 0.f;
        for (int k = 0; k < Kk; ++k) {
            __syncthreads();
            {
                float dzt[4][4];
                #pragma unroll
                for (int j = 0; j < 4; ++j)
                    #pragma unroll
                    for (int m = 0; m < 4; ++m) dzt[j][m] = 0.f;
                for (int v = 0; v < 25; ++v) {
                    f4 pa = *(const f4*)&psT[v][q0];
                    f4 ad = *(const f4*)&attD_s[k][v][w0];
                    #pragma unroll
                    for (int j = 0; j < 4; ++j)
                        #pragma unroll
                        for (int m = 0; m < 4; ++m) dzt[j][m] += pa[j] * ad[m];
                }
                #pragma unroll
                for (int j = 0; j < 4; ++j) {
                    f4 wv = { dzt[j][0], dzt[j][1], dzt[j][2], dzt[j][3] };
                    *(f4*)&dz_s[q0 + j][w0] = wv;
                }
            }
            __syncthreads();
            const float* wgp = dwdTg + k * 4096 + q0;
            #pragma unroll 8
            for (int c = 0; c < 64; ++c) {
                f4 wv = *(const f4*)&wgp[c * 64];
                f4 zv = *(const f4*)&dz_s[c][w0];
                #pragma unroll
                for (int j = 0; j < 4; ++j)
                    #pragma unroll
                    for (int m = 0; m < 4; ++m) acc[j][m] += wv[j] * zv[m];
            }
        }
        #pragma unroll
        for (int m = 0; m < 4; ++m) if (w0 + m < 25)
            #pragma unroll
            for (int j = 0; j < 4; ++j) {
                float a = acc[j][m]; s1_[j] += a; s2_[j] += a * a;
            }
    }
    float* red = (float*)dz_s;
    #pragma unroll
    for (int pass = 0; pass < 2; ++pass) {
        __syncthreads();
        #pragma unroll
        for (int j = 0; j < 4; ++j)
            red[(q0 + j) * 8 + tw8] = pass ? s2_[j] : s1_[j];
        __syncthreads();
        if (tid < 64) {
            float a = 0.f;
            #pragma unroll
            for (int q = 0; q < 8; ++q) a += red[tid * 8 + q];
            long pb = (((long)br * N_ + n) * TBc + tb) * 128;
            outp[pb + tid * 2 + pass] = a;
        }
    }
}

/* =================================================================
 * DECY1 v3 (proven best): 128 threads, sequential u, TTC=2,
 * pcT/yc staged in LDS. LDS 51200B -> 3 blocks/CU.
 * ================================================================= */
template<int TTC>
__global__ __launch_bounds__(128)
void decy1_kernel(const float* __restrict__ x,
                  const float* __restrict__ attEp,
                  const float* __restrict__ attDp,
                  const float* __restrict__ ewd,
                  const float* __restrict__ pcTg,
                  const float* __restrict__ ycb,
                  const float* __restrict__ dwdTg,
                  float* __restrict__ outp)
{
    constexpr int TBc = Tn / TTC;
    __shared__ __align__(16) float psT[2][25][68];
    __shared__ __align__(16) float dz_s[64][36];
    __shared__ __align__(16) float attD_s[2][Kk][25][32];
    __shared__ __align__(16) float ewdT_s[9][64];
    __shared__ __align__(16) float ez_s[2][9][28];
    __shared__ __align__(16) float pcT_s[2][6][64];
    __shared__ __align__(16) float yc_s[2][64][2];
    __shared__ float xs[2][3][25];

    int b = blockIdx.x, tb = b % TBc, n = b / TBc;
    int tid = threadIdx.x;
    int tq = tid >> 3;
    int tw8 = tid & 7;
    int q0 = tq * 4, w0 = tw8 * 4;

    for (int i = tid; i < 576; i += 128) {
        int kc = i >> 6, o = i & 63;
        int k = kc / 3, c = kc - k * 3;
        ewdT_s[kc][o] = ewd[(k * 64 + o) * 3 + c];
    }
    for (int i = tid; i < 1200; i += 128) {
        int u2 = i / 600, r = (i - u2 * 600) * 4;
        *(f4*)&((float*)attD_s)[u2 * 2400 + r] =
            *(const f4*)&attDp[(long)u2 * ADP_BR + n * 2400 + r];
    }
    for (int i = tid; i < 768; i += 128) ((float*)pcT_s)[i] = pcTg[i];
    for (int i = tid; i < 256; i += 128) ((float*)yc_s)[i] = ycb[i];

    for (int tt = 0; tt < TTC; ++tt) {
        int t = tb * TTC + tt;
        __syncthreads();   /* staging / prev rr readers done */
        for (int i = tid; i < 150; i += 128) {
            int uu = i / 75, r = i - uu * 75, c = r / 25, v = r - (r / 25) * 25;
            xs[uu][c][v] = x[(((long)n * 2 + uu) * 3 + c) * TV + t * 25 + v];
        }
        __syncthreads();
        for (int g = tid; g < 144; g += 128) {
            int u2 = g >= 72; int gg = g - u2 * 72;
            int kc = gg >> 3, wg = gg & 7;
            if (wg < 7) {
                int k = kc / 3, c = kc - k * 3;
                const float* aE = attEp + u2 * AEP_BR + n * 2100 + k * 700;
                float e0 = 0.f, e1 = 0.f, e2 = 0.f, e3 = 0.f;
                #pragma unroll
                for (int v = 0; v < 25; ++v) {
                    f4 ae = *(const f4*)&aE[v * 28 + wg * 4];
                    float xv = xs[u2][c][v];
                    e0 += xv * ae[0]; e1 += xv * ae[1];
                    e2 += xv * ae[2]; e3 += xv * ae[3];
                }
                f4 r = { e0, e1, e2, e3 };
                *(f4*)&ez_s[u2][kc][wg * 4] = r;
            }
        }
        __syncthreads();
        for (int g = tid; g < 800; g += 128) {
            int u2 = g >= 400; int gg = g - u2 * 400;
            int og = (gg & 15) << 2, w = gg >> 4;
            float y0 = 0.f, y1 = 0.f, y2 = 0.f, y3 = 0.f;
            #pragma unroll
            for (int kc = 0; kc < 9; ++kc) {
                f4 wt = *(const f4*)&ewdT_s[kc][og];
                float ev = ez_s[u2][kc][w];
                y0 += wt[0] * ev; y1 += wt[1] * ev;
                y2 += wt[2] * ev; y3 += wt[3] * ev;
            }
            const float* pcb = &pcT_s[u2][0][0];
            f4 al = *(const f4*)&pcb[0 * 64 + og];
            f4 be = *(const f4*)&pcb[1 * 64 + og];
            f4 d0 = *(const f4*)&pcb[2 * 64 + og];
            f4 d1 = *(const f4*)&pcb[3 * 64 + og];
            f4 d2 = *(const f4*)&pcb[4 * 64 + og];
            float x0 = xs[u2][0][w], x1 = xs[u2][1][w], x2 = xs[u2][2][w];
            f4 r;
            r[0] = fmaxf(al[0] * y0 + be[0] + d0[0] * x0 + d1[0] * x1 + d2[0] * x2, 0.f);
            r[1] = fmaxf(al[1] * y1 + be[1] + d0[1] * x0 + d1[1] * x1 + d2[1] * x2, 0.f);
            r[2] = fmaxf(al[2] * y2 + be[2] + d0[2] * x0 + d1[2] * x1 + d2[2] * x2, 0.f);
            r[3] = fmaxf(al[3] * y3 + be[3] + d0[3] * x0 + d1[3] * x1 + d2[3] * x2, 0.f);
            *(f4*)&psT[u2][w][og] = r;
        }
        for (int u2 = 0; u2 < 2; ++u2) {
            float acc[4][4];
            #pragma unroll
            for (int j = 0; j < 4; ++j)
                #pragma unroll
                for (int m = 0; m < 4; ++m) acc[j][m] = 0.f;
            for (int k = 0; k < Kk; ++k) {
                __syncthreads();
                {
                    float dzt[4][4];
                    #pragma unroll
                    for (int j = 0; j < 4; ++j)
                        #pragma unroll
                        for (int m = 0; m < 4; ++m) dzt[j][m] = 0.f;
                    for (int v = 0; v < 25; ++v) {
                        f4 pa = *(const f4*)&psT[u2][v][q0];
                        f4 ad = *(const f4*)&attD_s[u2][k][v][w0];
                        #pragma unroll
                        for (int j = 0; j < 4; ++j)
                            #pragma unroll
                            for (int m = 0; m < 4; ++m) dzt[j][m] += pa[j] * ad[m];
                    }
                    #pragma unroll
                    for (int j = 0; j < 4; ++j) {
                        f4 wv = { dzt[j][0], dzt[j][1], dzt[j][2], dzt[j][3] };
                        *(f4*)&dz_s[q0 + j][w0] = wv;
                    }
                }
                __syncthreads();
                const float* wgp = dwdTg + k * 4096 + q0;
                #pragma unroll 8
                for (int c = 0; c < 64; ++c) {
                    f4 wv = *(const f4*)&wgp[c * 64];
                    f4 zv = *(const f4*)&dz_s[c][w0];
                    #pragma unroll
                    for (int j = 0; j < 4; ++j)
                        #pragma unroll
                        for (int m = 0; m < 4; ++m) acc[j][m] += wv[j] * zv[m];
                }
            }
            const float* ycu = &yc_s[u2][0][0];
            #pragma unroll
            for (int m = 0; m < 4; ++m) {
                int w = w0 + m;
                if (w < 25) {
                    #pragma unroll
                    for (int j = 0; j < 4; ++j) {
                        float pd = ycu[(q0 + j) * 2] * acc[j][m]
                                 + ycu[(q0 + j) * 2 + 1] + psT[u2][w][q0 + j];
                        psT[u2][w][q0 + j] = fmaxf(pd, 0.f);
                    }
                }
            }
        }
        __syncthreads();
        for (int i = tid; i < 169; i += 128) {
            int tv = i / 13, tw2 = i % 13;
            int v0 = tv * 2, ww0 = tw2 * 2;
            float r00 = 0.f, r01 = 0.f, r10 = 0.f, r11 = 0.f;
            for (int c = 0; c < 64; c += 4) {
                f4 a0 = *(const f4*)&psT[0][v0][c];
                f4 a1 = *(const f4*)&psT[0][v0 + 1][c];
                f4 b0 = *(const f4*)&psT[1][ww0][c];
                f4 b1 = *(const f4*)&psT[1][ww0 + 1][c];
                #pragma unroll
                for (int q = 0; q < 4; ++q) {
                    r00 += a0[q] * b0[q]; r01 += a0[q] * b1[q];
                    r10 += a1[q] * b0[q]; r11 += a1[q] * b1[q];
                }
            }
            long ob = ((long)n * Tn + t) * VV;
            outp[ob + v0 * 25 + ww0] = r00;
            if (ww0 + 1 < 25)                outp[ob + v0 * 25 + ww0 + 1] = r01;
            if (v0 + 1 < 25)                 outp[ob + (v0 + 1) * 25 + ww0] = r10;
            if (v0 + 1 < 25 && ww0 + 1 < 25) outp[ob + (v0 + 1) * 25 + ww0 + 1] = r11;
        }
    }
}

/* DEC finalize — batched: 2 blocks (one per branch) */
__global__ __launch_bounds__(64)
void dec_fin_kernel(const float* __restrict__ partB, int nparts,
                    const float* __restrict__ dg, const float* __restrict__ dbt,
                    float* __restrict__ ycB)
{
    int br = blockIdx.x;
    const float* part = partB + (long)br * nparts * 128;
    float* yc = ycB + br * 128;
    int o = threadIdx.x;
    double s1 = 0, s2 = 0;
    for (int b = 0; b < nparts; ++b) { s1 += part[(long)b * 128 + o * 2]; s2 += part[(long)b * 128 + o * 2 + 1]; }
    double cnt = (double)N_ * Tn * Vn;
    double mean = s1 / cnt, var = s2 / cnt - mean * mean;
    double rsig = 1.0 / sqrt(var + 1e-5);
    double a = (double)dg[o] * rsig;
    yc[o * 2 + 0] = (float)a;
    yc[o * 2 + 1] = (float)((double)dbt[o] - a * mean);
}

/* BN stats over (n,v,w) per t */
__global__ __launch_bounds__(256)
void rrbn_kernel(const float* __restrict__ rr, float* __restrict__ tstats)
{
    int t = blockIdx.x;
    double s = 0.0, s2 = 0.0;
    for (int idx = threadIdx.x; idx < N_ * VV; idx += 256) {
        int n = idx / VV, j = idx % VV;
        float v = rr[((long)n * Tn + t) * VV + j];
        s += v; s2 += (double)v * v;
    }
    __shared__ double rs[256], rs2[256];
    int tid = threadIdx.x;
    rs[tid] = s; rs2[tid] = s2;
    __syncthreads();
    for (int off = 128; off > 0; off >>= 1) {
        if (tid < off) { rs[tid] += rs[tid + off]; rs2[tid] += rs2[tid + off]; }
        __syncthreads();
    }
    if (tid == 0) {
        double cnt = (double)N_ * VV;
        double mean = rs[0] / cnt;
        double var = rs2[0] / cnt - mean * mean;
        tstats[t * 2 + 0] = (float)mean;
        tstats[t * 2 + 1] = (float)(1.0 / sqrt(var + 1e-5));
    }
}

/* FINAL */
__global__ __launch_bounds__(128)
void final_kernel(const float* __restrict__ tstats,
                  const float* __restrict__ x, const float* __restrict__ iparam,
                  const float* __restrict__ tgamma, const float* __restrict__ tbeta,
                  float* out)
{
    int b = blockIdx.x;
    int t = b % Tn, n = b / Tn;
    __shared__ float xa_s[CIN][Vn], xb_s[CIN][Vn];
    __shared__ float ram_s[VV];
    __shared__ float da_s[Vn], db_s[Vn];
    __shared__ float varc[CIN];
    __shared__ float abf;
    int tid = threadIdx.x;

    for (int idx = tid; idx < 2 * CIN * Vn; idx += 128) {
        int half = idx / (CIN * Vn);
        int r = idx % (CIN * Vn);
        int c = r / Vn, v = r % Vn;
        float val = x[(((long)n * Mn + half) * CIN + c) * TV + t * Vn + v];
        if (half == 0) xa_s[c][v] = val; else xb_s[c][v] = val;
    }
    __syncthreads();
    if (tid < CIN) {
        float s = 0.f, s2 = 0.f;
        #pragma unroll
        for (int v = 0; v < Vn; ++v) { float q = xb_s[tid][v]; s += q; s2 += q * q; }
        float mean = s / Vn;
        varc[tid] = (s2 - Vn * mean * mean) / (Vn - 1);
    }
    __syncthreads();
    if (tid == 0) {
        float absum = varc[0] + varc[1] + varc[2];
        abf = (absum < 1e-4f) ? 0.f : 1.f;
    }
    float pct = 0.5f * (tanhf(iparam[0]) + 1.f);
    float mt = tstats[t * 2], rt = tstats[t * 2 + 1];
    float gt = tgamma[t], bt = tbeta[t];
    __syncthreads();

    for (int idx = tid; idx < VV; idx += 128) {
        int v = idx / Vn, w = idx % Vn;
        float rrv = out[(long)b * VV + idx];
        float rbn = gt * (rrv - mt) * rt + bt;
        float ramr = 0.5f * (tanhf(rbn) + 1.f);
        float gsum = 0.f;
        #pragma unroll
        for (int c = 0; c < CIN; ++c) {
            float d = expf(xa_s[c][v]) * expf(-xb_s[c][w]);
            float l = logf(d + 1e-5f);
            gsum += l * l;
        }
        float ramg = expf(-(1.f / 3.f) * gsum);
        float ram = pct * ramr + (1.f - pct) * ramg;
        ram *= abf;
        if (ram < 0.5f) ram = 0.f;
        ram_s[idx] = ram;
    }
    __syncthreads();
    if (tid < Vn) {
        float s = 0.f;
        #pragma unroll
        for (int v = 0; v < Vn; ++v) s += ram_s[v * Vn + tid];
        da_s[tid] = s;
    } else if (tid >= 64 && tid < 64 + Vn) {
        int v = tid - 64;
        float s = 0.f;
        #pragma unroll
        for (int w = 0; w < Vn; ++w) s += ram_s[v * Vn + w];
        db_s[v] = s;
    }
    __syncthreads();
    for (int idx = tid; idx < VV; idx += 128) {
        int v = idx / Vn, w = idx % Vn;
        float ram = ram_s[idx];
        out[(long)b * VV + idx] = ram * rsqrtf(db_s[v] * da_s[w] + 1e-5f);
    }
}

/* ================================================================= */
extern "C" void kernel_launch(void* const* d_in, const int* in_sizes, int n_in,
                              void* d_out, int out_size, void* d_ws, size_t ws_size,
                              hipStream_t stream)
{
    const float* x    = (const float*)d_in[0];
    const float* A    = (const float*)d_in[1];
    const float* ip   = (const float*)d_in[2];
    const float* rg   = (const float*)d_in[3];
    const float* rbta = (const float*)d_in[4];
    const float* ePA  = (const float*)d_in[5];
    const float* ewa  = (const float*)d_in[6];
    const float* eba  = (const float*)d_in[7];
    const float* ewb  = (const float*)d_in[8];
    const float* ebb  = (const float*)d_in[9];
    const float* ewd  = (const float*)d_in[10];
    const float* ebd  = (const float*)d_in[11];  (void)ebd;
    const float* eg   = (const float*)d_in[12];
    const float* ebt  = (const float*)d_in[13];
    const float* edw  = (const float*)d_in[14];
    const float* edb  = (const float*)d_in[15];
    const float* edg  = (const float*)d_in[16];
    const float* edbt = (const float*)d_in[17];
    const float* dPA  = (const float*)d_in[18];
    const float* dwa  = (const float*)d_in[19];
    const float* dba  = (const float*)d_in[20];
    const float* dwb  = (const float*)d_in[21];
    const float* dbb  = (const float*)d_in[22];
    const float* dwd  = (const float*)d_in[23];
    const float* dbd  = (const float*)d_in[24];  (void)dbd;
    const float* dg   = (const float*)d_in[25];
    const float* dbt  = (const float*)d_in[26];

    if (ws_size < (size_t)WS_REQ * sizeof(float)) return;

    float* ws    = (float*)d_ws;
    float* part  = ws + OFF_PART;
    float* attEp = ws + OFF_ATTEP;
    float* attDp = ws + OFF_ATTDP;
    double* covp = (double*)(ws + OFF_COV);
    float* pcT   = ws + OFF_PCT;
    float* yc    = ws + OFF_YC;
    float* tst   = ws + OFF_TST;
    float* dwdTg = ws + OFF_DWDT;
    float* wabTg = ws + OFF_WABT;
    float* outf  = (float*)d_out;

    tr_dwd_kernel<<<(Kk * CE * CE + 255) / 256, 256, 0, stream>>>(dwd, dwdTg);
    tr_wab_kernel<<<(CE * 96 + 255) / 256, 256, 0, stream>>>(dwa, dwb, wabTg);

    /* -------- both branches batched per dispatch --------
     * att partials -> d_out (2.4M floats), consumed immediately by
     * softmaxE before datt overwrites d_out with its own partials. */
    att_kernel<<<2 * N_ * Kk * ESEG, 640, 0, stream>>>(
        x, ewa, eba, ewb, ebb, outf);
    softmax_kernel<ESEG, 28><<<2 * N_ * Kk, 256, 0, stream>>>(outf, A, ePA, attEp);
    xcov_kernel<<<240, 256, 0, stream>>>(x, covp);
    ey_stat_kernel<<<2 * N_ * EYB, 256, 0, stream>>>(x, attEp, ewd, part);
    enc_fin_kernel<<<2, 64, 0, stream>>>(part, covp, eg, ebt, edw, edb, edg, edbt, pcT);
    /* datt partials -> d_out (7.2M floats), consumed by softmaxD */
    datt_kernel<<<2 * N_ * DSEG, 512, 0, stream>>>(
        x, attEp, ewd, pcT, wabTg, dba, dbb, outf);
    softmax_kernel<DSEG, 32><<<2 * N_ * Kk, 256, 0, stream>>>(outf, A, dPA, attDp);

    /* dec-y stats: one branch per block, TTC=5 -> 7680 blocks */
    decy0_kernel<5><<<2 * N_ * (Tn / 5), 128, 0, stream>>>(
        x, attEp, attDp, ewd, pcT, dwdTg, part);
    dec_fin_kernel<<<2, 64, 0, stream>>>(part, N_ * (Tn / 5), dg, dbt, yc);
    /* full dec out + rr: proven best (128 thr, seq-u, TTC=2) */
    decy1_kernel<2><<<N_ * (Tn / 2), 128, 0, stream>>>(
        x, attEp, attDp, ewd, pcT, yc, dwdTg, outf);

    rrbn_kernel<<<Tn, 256, 0, stream>>>(outf, tst);
    final_kernel<<<N_ * Tn, 128, 0, stream>>>(tst, x, ip, rg, rbta, outf);
}